// Round 1
// baseline (2513.553 us; speedup 1.0000x reference)
//
#include <hip/hip_runtime.h>
#include <hip/hip_bf16.h>

#define HH 256
#define DD 64
#define SS 49
#define BB 4800
#define PP 16384
#define NDP 32768
#define KWO 12544  // S*H

typedef unsigned int u32;
typedef unsigned short u16;

__device__ __forceinline__ float bf2f(__hip_bfloat16 h) { return __bfloat162float(h); }

__device__ __forceinline__ float wave_sum64(float v) {
#pragma unroll
  for (int off = 32; off > 0; off >>= 1) v += __shfl_xor(v, off);
  return v;
}

__device__ __forceinline__ float block_sum256(float v, float* red) {
  v = wave_sum64(v);
  int w = threadIdx.x >> 6;
  if ((threadIdx.x & 63) == 0) red[w] = v;
  __syncthreads();
  float r = red[0] + red[1] + red[2] + red[3];
  __syncthreads();
  return r;
}

// K0: WqT[h][k] = Wq[k][h]; w2[k] = sum_h Wq[k][h]*bk[h]; c2 = sum_h bq[h]*bk[h]
__global__ void k0_prep(const float* __restrict__ Wq, const float* __restrict__ bk,
                        const float* __restrict__ bq, float* __restrict__ WqT,
                        float* __restrict__ w2c2) {
  __shared__ float red[4];
  int k = blockIdx.x, h = threadIdx.x;
  float v = Wq[k * HH + h];
  WqT[h * HH + k] = v;
  float s = block_sum256(v * bk[h], red);
  if (h == 0) w2c2[k] = s;
  if (k == 0) {
    float s2 = block_sum256(bq[h] * bk[h], red);
    if (h == 0) w2c2[HH] = s2;
  }
}

// K1: per-b small MLP chain -> z[b][:], c1[b]
__global__ __launch_bounds__(256) void k1_perb(
    const float* __restrict__ pro, const float* __restrict__ posx,
    const float* __restrict__ bbox,
    const float* __restrict__ Wqs1, const float* __restrict__ bqs1,
    const float* __restrict__ Wqs2, const float* __restrict__ bqs2,
    const float* __restrict__ Wr1, const float* __restrict__ br1,
    const float* __restrict__ Wr2, const float* __restrict__ br2,
    const float* __restrict__ Wk, const float* __restrict__ WqT,
    const float* __restrict__ bq,
    float* __restrict__ z, float* __restrict__ c1) {
  __shared__ float a0[HH], a1[HH], a2[HH];
  __shared__ float red[4];
  __shared__ float refs[2];
  int b = blockIdx.x, t = threadIdx.x;
  a0[t] = pro[b * HH + t];
  __syncthreads();
  // t1 = relu(pro @ Wqs1 + bqs1)
  float acc = bqs1[t];
#pragma unroll 8
  for (int k = 0; k < HH; ++k) acc = fmaf(a0[k], Wqs1[k * HH + t], acc);
  a1[t] = fmaxf(acc, 0.f);
  __syncthreads();
  // pos_t = t1 @ Wqs2 + bqs2
  acc = bqs2[t];
#pragma unroll 8
  for (int k = 0; k < HH; ++k) acc = fmaf(a1[k], Wqs2[k * HH + t], acc);
  a2[t] = acc;
  __syncthreads();
  // r1 = relu(pro @ Wr1 + br1)
  acc = br1[t];
#pragma unroll 8
  for (int k = 0; k < HH; ++k) acc = fmaf(a0[k], Wr1[k * HH + t], acc);
  a1[t] = fmaxf(acc, 0.f);
  __syncthreads();
  float s0 = block_sum256(a1[t] * Wr2[t * 2 + 0], red);
  float s1 = block_sum256(a1[t] * Wr2[t * 2 + 1], red);
  if (t == 0) {
    refs[0] = 1.f / (1.f + __expf(-(s0 + br2[0])));
    refs[1] = 1.f / (1.f + __expf(-(s1 + br2[1])));
  }
  __syncthreads();
  // px_scaled: lo half * ref1/bb3, hi half * ref0/bb2
  float px = posx[b * HH + t] * a2[t];
  float sc = (t < HH / 2) ? (refs[1] / bbox[b * 4 + 3]) : (refs[0] / bbox[b * 4 + 2]);
  a0[t] = px * sc;
  __syncthreads();
  // y = px_scaled @ Wk   (no bias; bk handled via w2/c2 algebra)
  acc = 0.f;
#pragma unroll 8
  for (int k = 0; k < HH; ++k) acc = fmaf(a0[k], Wk[k * HH + t], acc);
  a1[t] = acc;
  __syncthreads();
  // z[k] = sum_h Wq[k][h]*y[h] = sum_h WqT[h][k]*y[h]
  acc = 0.f;
#pragma unroll 8
  for (int k = 0; k < HH; ++k) acc = fmaf(WqT[k * HH + t], a1[k], acc);
  z[b * HH + t] = acc;
  float sc1 = block_sum256(bq[t] * a1[t], red);
  if (t == 0) c1[b] = sc1;
}

// K2: fp[b,s] = posl[s]*(pos_img[s,b]·z[b] + c1[b]) + pos_img[s,b]·w2 + c2
__global__ __launch_bounds__(256) void k2_fp(
    const float* __restrict__ posi, const float* __restrict__ posl,
    const float* __restrict__ z, const float* __restrict__ c1,
    const float* __restrict__ w2c2, float* __restrict__ fp) {
  int b = blockIdx.x, t = threadIdx.x;
  int l = t & 63, w = t >> 6;
  float4 zv = *(const float4*)&z[b * HH + l * 4];
  float4 wv = *(const float4*)&w2c2[l * 4];
  float c1b = c1[b];
  float c2 = w2c2[HH];
  for (int s = w; s < SS; s += 4) {
    float4 pi = *(const float4*)&posi[((size_t)s * BB + b) * HH + l * 4];
    float d1 = pi.x * zv.x + pi.y * zv.y + pi.z * zv.z + pi.w * zv.w;
    float d2 = pi.x * wv.x + pi.y * wv.y + pi.z * wv.z + pi.w * wv.w;
#pragma unroll
    for (int off = 32; off > 0; off >>= 1) {
      d1 += __shfl_xor(d1, off);
      d2 += __shfl_xor(d2, off);
    }
    if (l == 0) fp[b * SS + s] = posl[s] * (d1 + c1b) + d2 + c2;
  }
}

// K3: parameters = pro @ Wd + bd  (M=4800, N=32768, K=256), fp32 compute -> bf16 out
__global__ __launch_bounds__(256) void k3_params(
    const float* __restrict__ pro, const float* __restrict__ Wd,
    const float* __restrict__ bd, __hip_bfloat16* __restrict__ params) {
  __shared__ float As[16][132];  // [k][m], padded
  __shared__ float Bs[16][128];  // [k][n]
  int t = threadIdx.x;
  int n0 = blockIdx.x * 128;
  int m0 = blockIdx.y * 128;
  int tm = t & 15, tn = t >> 4;
  float acc[8][8];
#pragma unroll
  for (int i = 0; i < 8; ++i)
#pragma unroll
    for (int j = 0; j < 8; ++j) acc[i][j] = 0.f;
  for (int k0 = 0; k0 < HH; k0 += 16) {
#pragma unroll
    for (int i = 0; i < 2; ++i) {
      int idx = t + 256 * i;  // 0..511
      // A: 128 rows x 16 k
      int row = idx >> 2, c4 = (idx & 3) * 4;
      int m = m0 + row;
      float4 v = {0.f, 0.f, 0.f, 0.f};
      if (m < BB) v = *(const float4*)&pro[m * HH + k0 + c4];
      As[c4 + 0][row] = v.x;
      As[c4 + 1][row] = v.y;
      As[c4 + 2][row] = v.z;
      As[c4 + 3][row] = v.w;
      // B: 16 k x 128 n
      int kr = idx >> 5, cb = (idx & 31) * 4;
      *(float4*)&Bs[kr][cb] = *(const float4*)&Wd[(size_t)(k0 + kr) * NDP + n0 + cb];
    }
    __syncthreads();
#pragma unroll
    for (int kk = 0; kk < 16; ++kk) {
      float a[8], bb_[8];
      *(float4*)&a[0] = *(const float4*)&As[kk][tm * 8];
      *(float4*)&a[4] = *(const float4*)&As[kk][tm * 8 + 4];
      *(float4*)&bb_[0] = *(const float4*)&Bs[kk][tn * 8];
      *(float4*)&bb_[4] = *(const float4*)&Bs[kk][tn * 8 + 4];
#pragma unroll
      for (int i = 0; i < 8; ++i)
#pragma unroll
        for (int j = 0; j < 8; ++j) acc[i][j] = fmaf(a[i], bb_[j], acc[i][j]);
    }
    __syncthreads();
  }
#pragma unroll
  for (int i = 0; i < 8; ++i) {
    int m = m0 + tm * 8 + i;
    if (m < BB) {
      union { u16 u[8]; uint4 v4; } pk;
#pragma unroll
      for (int j = 0; j < 8; ++j) {
        float v = acc[i][j] + bd[n0 + tn * 8 + j];
        __hip_bfloat16 hb = __float2bfloat16(v);
        pk.u[j] = *(u16*)&hb;
      }
      *(uint4*)&params[(size_t)m * NDP + n0 + tn * 8] = pk.v4;
    }
  }
}

// K4: per-b dynamic conv: f1 = feat@param1 + fp, LN1+relu, f2 = f1'@param2, LN2+relu -> bf16
__global__ __launch_bounds__(256) void k4_conv(
    const float* __restrict__ roi, const __hip_bfloat16* __restrict__ params,
    const float* __restrict__ fpbuf,
    const float* __restrict__ g1, const float* __restrict__ be1,
    const float* __restrict__ g2, const float* __restrict__ be2,
    __hip_bfloat16* __restrict__ f2ws) {
  int b = blockIdx.x;
  int t = threadIdx.x;
  int l = t & 63, w = t >> 6;
  __shared__ __hip_bfloat16 pbuf[PP];  // 32KB: param1, later param2
  __shared__ float dyn[SS * 128];      // 25088B: feats half; later f1s(3136)+fpr(49); later f2 bf16
  // stage param1
  {
    const u32* src = (const u32*)(params + (size_t)b * NDP);
    u32* dst = (u32*)pbuf;
    for (int i = 0; i < 32; ++i) dst[t + 256 * i] = src[t + 256 * i];
  }
  float acc[13];
#pragma unroll
  for (int i = 0; i < 13; ++i) acc[i] = 0.f;

  for (int half = 0; half < 2; ++half) {
    const int h0 = half * 128;
    __syncthreads();  // param1 staged (iter0) / feats reads done (iter1)
    for (int idx = t; idx < SS * 32; idx += 256) {
      int s = idx >> 5, c = (idx & 31) * 4;
      *(float4*)&dyn[s * 128 + c] =
          *(const float4*)&roi[((size_t)s * BB + b) * HH + h0 + c];
    }
    __syncthreads();
    for (int hq = 0; hq < 32; ++hq) {
      int hh = hq * 4;
      float pv0 = bf2f(pbuf[(h0 + hh + 0) * DD + l]);
      float pv1 = bf2f(pbuf[(h0 + hh + 1) * DD + l]);
      float pv2 = bf2f(pbuf[(h0 + hh + 2) * DD + l]);
      float pv3 = bf2f(pbuf[(h0 + hh + 3) * DD + l]);
#pragma unroll
      for (int i = 0; i < 13; ++i) {
        int s = w + 4 * i;
        if (s < SS) {
          float4 fv = *(const float4*)&dyn[s * 128 + hh];
          acc[i] = fmaf(fv.x, pv0, fmaf(fv.y, pv1, fmaf(fv.z, pv2, fmaf(fv.w, pv3, acc[i]))));
        }
      }
    }
  }
  __syncthreads();
  if (t < SS) dyn[SS * DD + t] = fpbuf[b * SS + t];  // fpr at [3136..3184]
  __syncthreads();
  // LN1 + relu -> f1s in dyn[0..3135]  (wave per s, lane = d)
  {
    float g1v = g1[l], b1v = be1[l];
#pragma unroll
    for (int i = 0; i < 13; ++i) {
      int s = w + 4 * i;
      if (s < SS) {
        float v = acc[i] + dyn[SS * DD + s];
        float m = wave_sum64(v) * (1.f / 64.f);
        float d = v - m;
        float var = wave_sum64(d * d) * (1.f / 64.f);
        float o = fmaxf(fmaf(d * rsqrtf(var + 1e-5f), g1v, b1v), 0.f);
        dyn[s * DD + l] = o;
      }
    }
  }
  __syncthreads();
  // stage param2 (overwrites param1)
  {
    const u32* src = (const u32*)(params + (size_t)b * NDP + PP);
    u32* dst = (u32*)pbuf;
    for (int i = 0; i < 32; ++i) dst[t + 256 * i] = src[t + 256 * i];
  }
  __syncthreads();
  // f2[s][t] = sum_d f1s[s][d] * param2[d][t]
  float acc2[SS];
#pragma unroll
  for (int s = 0; s < SS; ++s) acc2[s] = 0.f;
  for (int dq = 0; dq < 16; ++dq) {
    int d0 = dq * 4;
    float pv0 = bf2f(pbuf[(d0 + 0) * HH + t]);
    float pv1 = bf2f(pbuf[(d0 + 1) * HH + t]);
    float pv2 = bf2f(pbuf[(d0 + 2) * HH + t]);
    float pv3 = bf2f(pbuf[(d0 + 3) * HH + t]);
#pragma unroll
    for (int s = 0; s < SS; ++s) {
      float4 fv = *(const float4*)&dyn[s * DD + d0];
      acc2[s] = fmaf(fv.x, pv0, fmaf(fv.y, pv1, fmaf(fv.z, pv2, fmaf(fv.w, pv3, acc2[s]))));
    }
  }
  __syncthreads();  // f1s reads done; reuse dyn as bf16 f2 stage
  __hip_bfloat16* f2sh = (__hip_bfloat16*)dyn;
#pragma unroll
  for (int s = 0; s < SS; ++s) f2sh[s * HH + t] = __float2bfloat16(acc2[s]);
  __syncthreads();
  // LN2 + relu per s (wave per s, 4 h per lane) -> f2ws bf16
  {
    float4 g2v = *(const float4*)&g2[l * 4];
    float4 b2v = *(const float4*)&be2[l * 4];
#pragma unroll
    for (int i = 0; i < 13; ++i) {
      int s = w + 4 * i;
      if (s < SS) {
        float v0 = bf2f(f2sh[s * HH + l * 4 + 0]);
        float v1 = bf2f(f2sh[s * HH + l * 4 + 1]);
        float v2 = bf2f(f2sh[s * HH + l * 4 + 2]);
        float v3 = bf2f(f2sh[s * HH + l * 4 + 3]);
        float m = wave_sum64(v0 + v1 + v2 + v3) * (1.f / HH);
        float d0_ = v0 - m, d1_ = v1 - m, d2_ = v2 - m, d3_ = v3 - m;
        float var = wave_sum64(d0_ * d0_ + d1_ * d1_ + d2_ * d2_ + d3_ * d3_) * (1.f / HH);
        float r = rsqrtf(var + 1e-5f);
        float o0 = fmaxf(fmaf(d0_ * r, g2v.x, b2v.x), 0.f);
        float o1 = fmaxf(fmaf(d1_ * r, g2v.y, b2v.y), 0.f);
        float o2 = fmaxf(fmaf(d2_ * r, g2v.z, b2v.z), 0.f);
        float o3 = fmaxf(fmaf(d3_ * r, g2v.w, b2v.w), 0.f);
        union { u16 u[4]; uint2 v2_; } pk;
        __hip_bfloat16 hb;
        hb = __float2bfloat16(o0); pk.u[0] = *(u16*)&hb;
        hb = __float2bfloat16(o1); pk.u[1] = *(u16*)&hb;
        hb = __float2bfloat16(o2); pk.u[2] = *(u16*)&hb;
        hb = __float2bfloat16(o3); pk.u[3] = *(u16*)&hb;
        *(uint2*)&f2ws[(size_t)b * KWO + s * HH + l * 4] = pk.v2_;
      }
    }
  }
}

// K5: obuf = f2ws @ Wo + bo  (M=4800, N=256, K=12544)
__global__ __launch_bounds__(256) void k5_out(
    const __hip_bfloat16* __restrict__ f2ws, const float* __restrict__ Wo,
    const float* __restrict__ bo, float* __restrict__ obuf) {
  __shared__ float As[32][68];
  __shared__ float Bs[32][68];
  int t = threadIdx.x;
  int m0 = blockIdx.x * 64;
  int n0 = blockIdx.y * 64;
  int tm = t & 15, tn = t >> 4;
  float acc[4][4];
#pragma unroll
  for (int i = 0; i < 4; ++i)
#pragma unroll
    for (int j = 0; j < 4; ++j) acc[i][j] = 0.f;
  for (int k0 = 0; k0 < KWO; k0 += 32) {
    {
      int row = t >> 2, c = (t & 3) * 8;
      uint4 q = *(const uint4*)&f2ws[(size_t)(m0 + row) * KWO + k0 + c];
      u32 wq[4] = {q.x, q.y, q.z, q.w};
#pragma unroll
      for (int jj = 0; jj < 4; ++jj) {
        As[c + 2 * jj + 0][row] = __uint_as_float(wq[jj] << 16);
        As[c + 2 * jj + 1][row] = __uint_as_float(wq[jj] & 0xffff0000u);
      }
    }
#pragma unroll
    for (int i = 0; i < 2; ++i) {
      int idx = t + 256 * i;  // 0..511
      int kr = idx >> 4, cb = (idx & 15) * 4;
      *(float4*)&Bs[kr][cb] = *(const float4*)&Wo[(size_t)(k0 + kr) * HH + n0 + cb];
    }
    __syncthreads();
#pragma unroll
    for (int kk = 0; kk < 32; ++kk) {
      float a[4], bb_[4];
      *(float4*)&a[0] = *(const float4*)&As[kk][tm * 4];
      *(float4*)&bb_[0] = *(const float4*)&Bs[kk][tn * 4];
#pragma unroll
      for (int i = 0; i < 4; ++i)
#pragma unroll
        for (int j = 0; j < 4; ++j) acc[i][j] = fmaf(a[i], bb_[j], acc[i][j]);
    }
    __syncthreads();
  }
#pragma unroll
  for (int i = 0; i < 4; ++i)
#pragma unroll
    for (int j = 0; j < 4; ++j) {
      int m = m0 + tm * 4 + i;
      int n = n0 + tn * 4 + j;
      obuf[(size_t)m * HH + n] = acc[i][j] + bo[n];
    }
}

// K6: LN3 + relu -> out
__global__ __launch_bounds__(256) void k6_ln3(
    const float* __restrict__ obuf, const float* __restrict__ g3,
    const float* __restrict__ be3, float* __restrict__ out) {
  __shared__ float red[4];
  int b = blockIdx.x, t = threadIdx.x;
  float v = obuf[b * HH + t];
  float m = block_sum256(v, red) * (1.f / HH);
  float d = v - m;
  float var = block_sum256(d * d, red) * (1.f / HH);
  out[b * HH + t] = fmaxf(fmaf(d * rsqrtf(var + 1e-5f), g3[t], be3[t]), 0.f);
}

extern "C" void kernel_launch(void* const* d_in, const int* in_sizes, int n_in,
                              void* d_out, int out_size, void* d_ws, size_t ws_size,
                              hipStream_t stream) {
  const float* pro  = (const float*)d_in[0];
  const float* roi  = (const float*)d_in[1];
  const float* posx = (const float*)d_in[2];
  const float* posi = (const float*)d_in[3];
  const float* posl = (const float*)d_in[4];
  const float* bbox = (const float*)d_in[5];
  const float* Wd   = (const float*)d_in[6];
  const float* bd   = (const float*)d_in[7];
  const float* Wqs1 = (const float*)d_in[8];
  const float* bqs1 = (const float*)d_in[9];
  const float* Wqs2 = (const float*)d_in[10];
  const float* bqs2 = (const float*)d_in[11];
  const float* Wr1  = (const float*)d_in[12];
  const float* br1  = (const float*)d_in[13];
  const float* Wr2  = (const float*)d_in[14];
  const float* br2  = (const float*)d_in[15];
  const float* Wq   = (const float*)d_in[16];
  const float* bq   = (const float*)d_in[17];
  const float* Wk   = (const float*)d_in[18];
  const float* bk   = (const float*)d_in[19];
  const float* g1   = (const float*)d_in[20];
  const float* be1  = (const float*)d_in[21];
  const float* g2   = (const float*)d_in[22];
  const float* be2  = (const float*)d_in[23];
  const float* g3   = (const float*)d_in[24];
  const float* be3  = (const float*)d_in[25];
  const float* Wo   = (const float*)d_in[26];
  const float* bo   = (const float*)d_in[27];

  // ws layout (bytes), all 16B aligned; total ~426 MiB
  char* ws = (char*)d_ws;
  __hip_bfloat16* params = (__hip_bfloat16*)(ws + 0ull);          // 314572800
  __hip_bfloat16* f2ws   = (__hip_bfloat16*)(ws + 314572800ull);  // 120422400
  float* z    = (float*)(ws + 434995200ull);                      // 4915200
  float* obuf = (float*)(ws + 439910400ull);                      // 4915200
  float* fp   = (float*)(ws + 444825600ull);                      // 940800
  float* c1   = (float*)(ws + 445766400ull);                      // 19200
  float* WqT  = (float*)(ws + 445785600ull);                      // 262144
  float* w2c2 = (float*)(ws + 446047744ull);                      // 1040

  k0_prep<<<dim3(256), dim3(256), 0, stream>>>(Wq, bk, bq, WqT, w2c2);
  k1_perb<<<dim3(BB), dim3(256), 0, stream>>>(pro, posx, bbox, Wqs1, bqs1, Wqs2, bqs2,
                                              Wr1, br1, Wr2, br2, Wk, WqT, bq, z, c1);
  k2_fp<<<dim3(BB), dim3(256), 0, stream>>>(posi, posl, z, c1, w2c2, fp);
  k3_params<<<dim3(NDP / 128, (BB + 127) / 128), dim3(256), 0, stream>>>(pro, Wd, bd, params);
  k4_conv<<<dim3(BB), dim3(256), 0, stream>>>(roi, params, fp, g1, be1, g2, be2, f2ws);
  k5_out<<<dim3(BB / 64, HH / 64), dim3(256), 0, stream>>>(f2ws, Wo, bo, obuf);
  k6_ln3<<<dim3(BB), dim3(256), 0, stream>>>(obuf, g3, be3, (float*)d_out);
}

// Round 3
// 1815.921 us; speedup vs baseline: 1.3842x; 1.3842x over previous
//
#include <hip/hip_runtime.h>
#include <hip/hip_bf16.h>

#define HH 256
#define DD 64
#define SS 49
#define BB 4800
#define PP 16384
#define NDP 32768
#define KWO 12544  // S*H
#define MPAD 4864  // BB padded to 128

typedef unsigned int u32;
typedef unsigned short u16;
typedef __attribute__((ext_vector_type(8))) short bf16x8;
typedef __attribute__((ext_vector_type(4))) float f32x4;

__device__ __forceinline__ float bf2f(__hip_bfloat16 h) { return __bfloat162float(h); }

__device__ __forceinline__ void load_lds16(const void* g, void* l) {
  __builtin_amdgcn_global_load_lds(
      (const __attribute__((address_space(1))) unsigned int*)g,
      (__attribute__((address_space(3))) unsigned int*)l, 16, 0, 0);
}

__device__ __forceinline__ float wave_sum64(float v) {
#pragma unroll
  for (int off = 32; off > 0; off >>= 1) v += __shfl_xor(v, off);
  return v;
}

__device__ __forceinline__ float block_sum256(float v, float* red) {
  v = wave_sum64(v);
  int w = threadIdx.x >> 6;
  if ((threadIdx.x & 63) == 0) red[w] = v;
  __syncthreads();
  float r = red[0] + red[1] + red[2] + red[3];
  __syncthreads();
  return r;
}

// K0: WqT[h][k] = Wq[k][h]; w2[k] = sum_h Wq[k][h]*bk[h]; c2 = sum_h bq[h]*bk[h]
__global__ void k0_prep(const float* __restrict__ Wq, const float* __restrict__ bk,
                        const float* __restrict__ bq, float* __restrict__ WqT,
                        float* __restrict__ w2c2) {
  __shared__ float red[4];
  int k = blockIdx.x, h = threadIdx.x;
  float v = Wq[k * HH + h];
  WqT[h * HH + k] = v;
  float s = block_sum256(v * bk[h], red);
  if (h == 0) w2c2[k] = s;
  if (k == 0) {
    float s2 = block_sum256(bq[h] * bk[h], red);
    if (h == 0) w2c2[HH] = s2;
  }
}

// K1: per-b small MLP chain -> z[b][:], c1[b]
__global__ __launch_bounds__(256) void k1_perb(
    const float* __restrict__ pro, const float* __restrict__ posx,
    const float* __restrict__ bbox,
    const float* __restrict__ Wqs1, const float* __restrict__ bqs1,
    const float* __restrict__ Wqs2, const float* __restrict__ bqs2,
    const float* __restrict__ Wr1, const float* __restrict__ br1,
    const float* __restrict__ Wr2, const float* __restrict__ br2,
    const float* __restrict__ Wk, const float* __restrict__ WqT,
    const float* __restrict__ bq,
    float* __restrict__ z, float* __restrict__ c1) {
  __shared__ float a0[HH], a1[HH], a2[HH];
  __shared__ float red[4];
  __shared__ float refs[2];
  int b = blockIdx.x, t = threadIdx.x;
  a0[t] = pro[b * HH + t];
  __syncthreads();
  float acc = bqs1[t];
#pragma unroll 8
  for (int k = 0; k < HH; ++k) acc = fmaf(a0[k], Wqs1[k * HH + t], acc);
  a1[t] = fmaxf(acc, 0.f);
  __syncthreads();
  acc = bqs2[t];
#pragma unroll 8
  for (int k = 0; k < HH; ++k) acc = fmaf(a1[k], Wqs2[k * HH + t], acc);
  a2[t] = acc;
  __syncthreads();
  acc = br1[t];
#pragma unroll 8
  for (int k = 0; k < HH; ++k) acc = fmaf(a0[k], Wr1[k * HH + t], acc);
  a1[t] = fmaxf(acc, 0.f);
  __syncthreads();
  float s0 = block_sum256(a1[t] * Wr2[t * 2 + 0], red);
  float s1 = block_sum256(a1[t] * Wr2[t * 2 + 1], red);
  if (t == 0) {
    refs[0] = 1.f / (1.f + __expf(-(s0 + br2[0])));
    refs[1] = 1.f / (1.f + __expf(-(s1 + br2[1])));
  }
  __syncthreads();
  float px = posx[b * HH + t] * a2[t];
  float sc = (t < HH / 2) ? (refs[1] / bbox[b * 4 + 3]) : (refs[0] / bbox[b * 4 + 2]);
  a0[t] = px * sc;
  __syncthreads();
  acc = 0.f;
#pragma unroll 8
  for (int k = 0; k < HH; ++k) acc = fmaf(a0[k], Wk[k * HH + t], acc);
  a1[t] = acc;
  __syncthreads();
  acc = 0.f;
#pragma unroll 8
  for (int k = 0; k < HH; ++k) acc = fmaf(WqT[k * HH + t], a1[k], acc);
  z[b * HH + t] = acc;
  float sc1 = block_sum256(bq[t] * a1[t], red);
  if (t == 0) c1[b] = sc1;
}

// K2: fp[b,s] = posl[s]*(pos_img[s,b]·z[b] + c1[b]) + pos_img[s,b]·w2 + c2
__global__ __launch_bounds__(256) void k2_fp(
    const float* __restrict__ posi, const float* __restrict__ posl,
    const float* __restrict__ z, const float* __restrict__ c1,
    const float* __restrict__ w2c2, float* __restrict__ fp) {
  int b = blockIdx.x, t = threadIdx.x;
  int l = t & 63, w = t >> 6;
  float4 zv = *(const float4*)&z[b * HH + l * 4];
  float4 wv = *(const float4*)&w2c2[l * 4];
  float c1b = c1[b];
  float c2 = w2c2[HH];
  for (int s = w; s < SS; s += 4) {
    float4 pi = *(const float4*)&posi[((size_t)s * BB + b) * HH + l * 4];
    float d1 = pi.x * zv.x + pi.y * zv.y + pi.z * zv.z + pi.w * zv.w;
    float d2 = pi.x * wv.x + pi.y * wv.y + pi.z * wv.z + pi.w * wv.w;
#pragma unroll
    for (int off = 32; off > 0; off >>= 1) {
      d1 += __shfl_xor(d1, off);
      d2 += __shfl_xor(d2, off);
    }
    if (l == 0) fp[b * SS + s] = posl[s] * (d1 + c1b) + d2 + c2;
  }
}

// cast pro -> bf16, padded to MPAD rows (zeros in pad)
__global__ __launch_bounds__(256) void kc_pro(const float* __restrict__ pro,
                                              u16* __restrict__ proh) {
  int tg = blockIdx.x * 256 + threadIdx.x;
  int e0 = tg * 8;  // MPAD*256/8 threads
  int row = e0 >> 8;
  union { u16 u[8]; uint4 v; } pk;
  if (row < BB) {
    float4 v0 = *(const float4*)&pro[e0];
    float4 v1 = *(const float4*)&pro[e0 + 4];
    float vv[8] = {v0.x, v0.y, v0.z, v0.w, v1.x, v1.y, v1.z, v1.w};
#pragma unroll
    for (int i = 0; i < 8; ++i) {
      __hip_bfloat16 hb = __float2bfloat16(vv[i]);
      pk.u[i] = *(u16*)&hb;
    }
  } else {
    pk.v = make_uint4(0, 0, 0, 0);
  }
  *(uint4*)&proh[e0] = pk.v;
}

// transpose+cast Wd (256 x 32768 f32) -> WdT (32768 x 256 bf16)
__global__ __launch_bounds__(256) void kc_wdt(const float* __restrict__ Wd,
                                              u16* __restrict__ wdt) {
  __shared__ float tile[32][33];
  int n0 = blockIdx.x * 32;
  int k0 = blockIdx.y * 32;
  int t = threadIdx.x;
  {
    int kk = t >> 3, nn = (t & 7) * 4;
    float4 v = *(const float4*)&Wd[(size_t)(k0 + kk) * NDP + n0 + nn];
    tile[kk][nn + 0] = v.x;
    tile[kk][nn + 1] = v.y;
    tile[kk][nn + 2] = v.z;
    tile[kk][nn + 3] = v.w;
  }
  __syncthreads();
  {
    int nn = t >> 3, kk = (t & 7) * 4;
    union { u16 u[4]; uint2 v; } pk;
#pragma unroll
    for (int i = 0; i < 4; ++i) {
      __hip_bfloat16 hb = __float2bfloat16(tile[kk + i][nn]);
      pk.u[i] = *(u16*)&hb;
    }
    *(uint2*)&wdt[(size_t)(n0 + nn) * HH + k0 + kk] = pk.v;
  }
}

// K3: params = proh @ WdT^T + bd via bf16 MFMA. M=4800(pad 4864), N=32768, K=256.
__global__ __launch_bounds__(256) void k3_mfma(const u16* __restrict__ proh,
                                               const u16* __restrict__ wdt,
                                               const float* __restrict__ bd,
                                               u16* __restrict__ params) {
  __shared__ char smem[32768];
  u16* Al = (u16*)smem;           // [128][32] bf16
  u16* Bl = (u16*)(smem + 8192);  // [128][32] bf16 (rows = n)
  const int t = threadIdx.x;
  const int w = t >> 6, l = t & 63;
  const int n0 = blockIdx.x * 128;
  const int m0 = blockIdx.y * 128;
  const int wr = w >> 1, wc = w & 1;
  f32x4 acc[4][4] = {};

  for (int k0 = 0; k0 < HH; k0 += 32) {
#pragma unroll
    for (int i = 0; i < 2; ++i) {
      int c = i * 256 + t;            // chunk id, 16B each
      int r = c >> 2, kq = (c & 3) * 8;
      // wave-uniform LDS dest: chunk base of this wave
      int wbase = (i * 256 + (w << 6)) * 8;  // elements
      load_lds16(proh + (size_t)(m0 + r) * HH + k0 + kq, Al + wbase);
      load_lds16(wdt + (size_t)(n0 + r) * HH + k0 + kq, Bl + wbase);
    }
    __syncthreads();
    bf16x8 af[4], bfr[4];
#pragma unroll
    for (int mi = 0; mi < 4; ++mi)
      af[mi] = *(const bf16x8*)&Al[(wr * 64 + mi * 16 + (l & 15)) * 32 + (l >> 4) * 8];
#pragma unroll
    for (int ni = 0; ni < 4; ++ni)
      bfr[ni] = *(const bf16x8*)&Bl[(wc * 64 + ni * 16 + (l & 15)) * 32 + (l >> 4) * 8];
#pragma unroll
    for (int mi = 0; mi < 4; ++mi)
#pragma unroll
      for (int ni = 0; ni < 4; ++ni)
        acc[mi][ni] = __builtin_amdgcn_mfma_f32_16x16x32_bf16(af[mi], bfr[ni], acc[mi][ni], 0, 0, 0);
    __syncthreads();
  }
  // epilogue: bias + bf16 -> LDS tile, then coalesced 16B stores
  u16* cb = (u16*)smem;  // [128][128] bf16
#pragma unroll
  for (int ni = 0; ni < 4; ++ni) {
    int col = wc * 64 + ni * 16 + (l & 15);
    float bias = bd[n0 + col];
#pragma unroll
    for (int mi = 0; mi < 4; ++mi) {
#pragma unroll
      for (int j = 0; j < 4; ++j) {
        int row = wr * 64 + mi * 16 + ((l >> 4) << 2) + j;
        __hip_bfloat16 hb = __float2bfloat16(acc[mi][ni][j] + bias);
        cb[row * 128 + col] = *(u16*)&hb;
      }
    }
  }
  __syncthreads();
#pragma unroll
  for (int i = 0; i < 8; ++i) {
    int idx = i * 256 + t;
    int row = idx >> 4, cc = (idx & 15) * 8;
    if (m0 + row < BB)
      *(uint4*)&params[(size_t)(m0 + row) * NDP + n0 + cc] = *(const uint4*)&cb[row * 128 + cc];
  }
}

// K4: per-b dynamic conv: f1 = feat@param1 + fp, LN1+relu, f2 = f1'@param2, LN2+relu -> bf16
__global__ __launch_bounds__(256) void k4_conv(
    const float* __restrict__ roi, const __hip_bfloat16* __restrict__ params,
    const float* __restrict__ fpbuf,
    const float* __restrict__ g1, const float* __restrict__ be1,
    const float* __restrict__ g2, const float* __restrict__ be2,
    __hip_bfloat16* __restrict__ f2ws) {
  int b = blockIdx.x;
  int t = threadIdx.x;
  int l = t & 63, w = t >> 6;
  __shared__ __hip_bfloat16 pbuf[PP];
  __shared__ float dyn[SS * 128];
  {
    const u32* src = (const u32*)(params + (size_t)b * NDP);
    u32* dst = (u32*)pbuf;
    for (int i = 0; i < 32; ++i) dst[t + 256 * i] = src[t + 256 * i];
  }
  float acc[13];
#pragma unroll
  for (int i = 0; i < 13; ++i) acc[i] = 0.f;

  for (int half = 0; half < 2; ++half) {
    const int h0 = half * 128;
    __syncthreads();
    for (int idx = t; idx < SS * 32; idx += 256) {
      int s = idx >> 5, c = (idx & 31) * 4;
      *(float4*)&dyn[s * 128 + c] =
          *(const float4*)&roi[((size_t)s * BB + b) * HH + h0 + c];
    }
    __syncthreads();
    for (int hq = 0; hq < 32; ++hq) {
      int hh = hq * 4;
      float pv0 = bf2f(pbuf[(h0 + hh + 0) * DD + l]);
      float pv1 = bf2f(pbuf[(h0 + hh + 1) * DD + l]);
      float pv2 = bf2f(pbuf[(h0 + hh + 2) * DD + l]);
      float pv3 = bf2f(pbuf[(h0 + hh + 3) * DD + l]);
#pragma unroll
      for (int i = 0; i < 13; ++i) {
        int s = w + 4 * i;
        if (s < SS) {
          float4 fv = *(const float4*)&dyn[s * 128 + hh];
          acc[i] = fmaf(fv.x, pv0, fmaf(fv.y, pv1, fmaf(fv.z, pv2, fmaf(fv.w, pv3, acc[i]))));
        }
      }
    }
  }
  __syncthreads();
  if (t < SS) dyn[SS * DD + t] = fpbuf[b * SS + t];
  __syncthreads();
  {
    float g1v = g1[l], b1v = be1[l];
#pragma unroll
    for (int i = 0; i < 13; ++i) {
      int s = w + 4 * i;
      if (s < SS) {
        float v = acc[i] + dyn[SS * DD + s];
        float m = wave_sum64(v) * (1.f / 64.f);
        float d = v - m;
        float var = wave_sum64(d * d) * (1.f / 64.f);
        float o = fmaxf(fmaf(d * rsqrtf(var + 1e-5f), g1v, b1v), 0.f);
        dyn[s * DD + l] = o;
      }
    }
  }
  __syncthreads();
  {
    const u32* src = (const u32*)(params + (size_t)b * NDP + PP);
    u32* dst = (u32*)pbuf;
    for (int i = 0; i < 32; ++i) dst[t + 256 * i] = src[t + 256 * i];
  }
  __syncthreads();
  float acc2[SS];
#pragma unroll
  for (int s = 0; s < SS; ++s) acc2[s] = 0.f;
  for (int dq = 0; dq < 16; ++dq) {
    int d0 = dq * 4;
    float pv0 = bf2f(pbuf[(d0 + 0) * HH + t]);
    float pv1 = bf2f(pbuf[(d0 + 1) * HH + t]);
    float pv2 = bf2f(pbuf[(d0 + 2) * HH + t]);
    float pv3 = bf2f(pbuf[(d0 + 3) * HH + t]);
#pragma unroll
    for (int s = 0; s < SS; ++s) {
      float4 fv = *(const float4*)&dyn[s * DD + d0];
      acc2[s] = fmaf(fv.x, pv0, fmaf(fv.y, pv1, fmaf(fv.z, pv2, fmaf(fv.w, pv3, acc2[s]))));
    }
  }
  __syncthreads();
  __hip_bfloat16* f2sh = (__hip_bfloat16*)dyn;
#pragma unroll
  for (int s = 0; s < SS; ++s) f2sh[s * HH + t] = __float2bfloat16(acc2[s]);
  __syncthreads();
  {
    float4 g2v = *(const float4*)&g2[l * 4];
    float4 b2v = *(const float4*)&be2[l * 4];
#pragma unroll
    for (int i = 0; i < 13; ++i) {
      int s = w + 4 * i;
      if (s < SS) {
        float v0 = bf2f(f2sh[s * HH + l * 4 + 0]);
        float v1 = bf2f(f2sh[s * HH + l * 4 + 1]);
        float v2 = bf2f(f2sh[s * HH + l * 4 + 2]);
        float v3 = bf2f(f2sh[s * HH + l * 4 + 3]);
        float m = wave_sum64(v0 + v1 + v2 + v3) * (1.f / HH);
        float d0_ = v0 - m, d1_ = v1 - m, d2_ = v2 - m, d3_ = v3 - m;
        float var = wave_sum64(d0_ * d0_ + d1_ * d1_ + d2_ * d2_ + d3_ * d3_) * (1.f / HH);
        float r = rsqrtf(var + 1e-5f);
        float o0 = fmaxf(fmaf(d0_ * r, g2v.x, b2v.x), 0.f);
        float o1 = fmaxf(fmaf(d1_ * r, g2v.y, b2v.y), 0.f);
        float o2 = fmaxf(fmaf(d2_ * r, g2v.z, b2v.z), 0.f);
        float o3 = fmaxf(fmaf(d3_ * r, g2v.w, b2v.w), 0.f);
        union { u16 u[4]; uint2 v2_; } pk;
        __hip_bfloat16 hb;
        hb = __float2bfloat16(o0); pk.u[0] = *(u16*)&hb;
        hb = __float2bfloat16(o1); pk.u[1] = *(u16*)&hb;
        hb = __float2bfloat16(o2); pk.u[2] = *(u16*)&hb;
        hb = __float2bfloat16(o3); pk.u[3] = *(u16*)&hb;
        *(uint2*)&f2ws[(size_t)b * KWO + s * HH + l * 4] = pk.v2_;
      }
    }
  }
}

// K5: obuf = f2ws @ Wo + bo  (M=4800, N=256, K=12544)
__global__ __launch_bounds__(256) void k5_out(
    const __hip_bfloat16* __restrict__ f2ws, const float* __restrict__ Wo,
    const float* __restrict__ bo, float* __restrict__ obuf) {
  __shared__ float As[32][68];
  __shared__ float Bs[32][68];
  int t = threadIdx.x;
  int m0 = blockIdx.x * 64;
  int n0 = blockIdx.y * 64;
  int tm = t & 15, tn = t >> 4;
  float acc[4][4];
#pragma unroll
  for (int i = 0; i < 4; ++i)
#pragma unroll
    for (int j = 0; j < 4; ++j) acc[i][j] = 0.f;
  for (int k0 = 0; k0 < KWO; k0 += 32) {
    {
      int row = t >> 2, c = (t & 3) * 8;
      uint4 q = *(const uint4*)&f2ws[(size_t)(m0 + row) * KWO + k0 + c];
      u32 wq[4] = {q.x, q.y, q.z, q.w};
#pragma unroll
      for (int jj = 0; jj < 4; ++jj) {
        As[c + 2 * jj + 0][row] = __uint_as_float(wq[jj] << 16);
        As[c + 2 * jj + 1][row] = __uint_as_float(wq[jj] & 0xffff0000u);
      }
    }
#pragma unroll
    for (int i = 0; i < 2; ++i) {
      int idx = t + 256 * i;
      int kr = idx >> 4, cb = (idx & 15) * 4;
      *(float4*)&Bs[kr][cb] = *(const float4*)&Wo[(size_t)(k0 + kr) * HH + n0 + cb];
    }
    __syncthreads();
#pragma unroll
    for (int kk = 0; kk < 32; ++kk) {
      float a[4], bb_[4];
      *(float4*)&a[0] = *(const float4*)&As[kk][tm * 4];
      *(float4*)&bb_[0] = *(const float4*)&Bs[kk][tn * 4];
#pragma unroll
      for (int i = 0; i < 4; ++i)
#pragma unroll
        for (int j = 0; j < 4; ++j) acc[i][j] = fmaf(a[i], bb_[j], acc[i][j]);
    }
    __syncthreads();
  }
#pragma unroll
  for (int i = 0; i < 4; ++i)
#pragma unroll
    for (int j = 0; j < 4; ++j) {
      int m = m0 + tm * 4 + i;
      int n = n0 + tn * 4 + j;
      obuf[(size_t)m * HH + n] = acc[i][j] + bo[n];
    }
}

// K6: LN3 + relu -> out
__global__ __launch_bounds__(256) void k6_ln3(
    const float* __restrict__ obuf, const float* __restrict__ g3,
    const float* __restrict__ be3, float* __restrict__ out) {
  __shared__ float red[4];
  int b = blockIdx.x, t = threadIdx.x;
  float v = obuf[b * HH + t];
  float m = block_sum256(v, red) * (1.f / HH);
  float d = v - m;
  float var = block_sum256(d * d, red) * (1.f / HH);
  out[b * HH + t] = fmaxf(fmaf(d * rsqrtf(var + 1e-5f), g3[t], be3[t]), 0.f);
}

extern "C" void kernel_launch(void* const* d_in, const int* in_sizes, int n_in,
                              void* d_out, int out_size, void* d_ws, size_t ws_size,
                              hipStream_t stream) {
  const float* pro  = (const float*)d_in[0];
  const float* roi  = (const float*)d_in[1];
  const float* posx = (const float*)d_in[2];
  const float* posi = (const float*)d_in[3];
  const float* posl = (const float*)d_in[4];
  const float* bbox = (const float*)d_in[5];
  const float* Wd   = (const float*)d_in[6];
  const float* bd   = (const float*)d_in[7];
  const float* Wqs1 = (const float*)d_in[8];
  const float* bqs1 = (const float*)d_in[9];
  const float* Wqs2 = (const float*)d_in[10];
  const float* bqs2 = (const float*)d_in[11];
  const float* Wr1  = (const float*)d_in[12];
  const float* br1  = (const float*)d_in[13];
  const float* Wr2  = (const float*)d_in[14];
  const float* br2  = (const float*)d_in[15];
  const float* Wq   = (const float*)d_in[16];
  const float* bq   = (const float*)d_in[17];
  const float* Wk   = (const float*)d_in[18];
  const float* bk   = (const float*)d_in[19];
  const float* g1   = (const float*)d_in[20];
  const float* be1  = (const float*)d_in[21];
  const float* g2   = (const float*)d_in[22];
  const float* be2  = (const float*)d_in[23];
  const float* g3   = (const float*)d_in[24];
  const float* be3  = (const float*)d_in[25];
  const float* Wo   = (const float*)d_in[26];
  const float* bo   = (const float*)d_in[27];

  // ws layout (bytes). proh/WdT alias the f2ws region (dead by the time K4 writes f2ws).
  char* ws = (char*)d_ws;
  __hip_bfloat16* params = (__hip_bfloat16*)(ws + 0ull);          // 314572800
  __hip_bfloat16* f2ws   = (__hip_bfloat16*)(ws + 314572800ull);  // 120422400
  u16* proh = (u16*)(ws + 314572800ull);                          // 2490368 (alias f2ws)
  u16* wdt  = (u16*)(ws + 317063168ull);                          // 16777216 (alias f2ws)
  float* z    = (float*)(ws + 434995200ull);                      // 4915200
  float* obuf = (float*)(ws + 439910400ull);                      // 4915200
  float* fp   = (float*)(ws + 444825600ull);                      // 940800
  float* c1   = (float*)(ws + 445766400ull);                      // 19200
  float* WqT  = (float*)(ws + 445785600ull);                      // 262144
  float* w2c2 = (float*)(ws + 446047744ull);                      // 1040

  k0_prep<<<dim3(256), dim3(256), 0, stream>>>(Wq, bk, bq, WqT, w2c2);
  k1_perb<<<dim3(BB), dim3(256), 0, stream>>>(pro, posx, bbox, Wqs1, bqs1, Wqs2, bqs2,
                                              Wr1, br1, Wr2, br2, Wk, WqT, bq, z, c1);
  k2_fp<<<dim3(BB), dim3(256), 0, stream>>>(posi, posl, z, c1, w2c2, fp);
  kc_pro<<<dim3(MPAD * HH / 8 / 256), dim3(256), 0, stream>>>(pro, proh);
  kc_wdt<<<dim3(NDP / 32, HH / 32), dim3(256), 0, stream>>>(Wd, wdt);
  k3_mfma<<<dim3(NDP / 128, MPAD / 128), dim3(256), 0, stream>>>(proh, wdt, bd,
                                                                 (u16*)params);
  k4_conv<<<dim3(BB), dim3(256), 0, stream>>>(roi, params, fp, g1, be1, g2, be2, f2ws);
  k5_out<<<dim3(BB / 64, HH / 64), dim3(256), 0, stream>>>(f2ws, Wo, bo, obuf);
  k6_ln3<<<dim3(BB), dim3(256), 0, stream>>>(obuf, g3, be3, (float*)d_out);
}

// Round 4
// 1178.022 us; speedup vs baseline: 2.1337x; 1.5415x over previous
//
#include <hip/hip_runtime.h>
#include <hip/hip_bf16.h>

#define HH 256
#define DD 64
#define SS 49
#define BB 4800
#define PP 16384
#define NDP 32768
#define KWO 12544  // S*H
#define MPAD 4864  // BB padded to 128
#define SK 8       // split-K factor for K5
#define KCH 1568   // KWO / SK = 49 * 32

typedef unsigned int u32;
typedef unsigned short u16;
typedef __attribute__((ext_vector_type(8))) short bf16x8;
typedef __attribute__((ext_vector_type(4))) float f32x4;

__device__ __forceinline__ float bf2f(__hip_bfloat16 h) { return __bfloat162float(h); }

__device__ __forceinline__ void load_lds16(const void* g, void* l) {
  __builtin_amdgcn_global_load_lds(
      (const __attribute__((address_space(1))) unsigned int*)g,
      (__attribute__((address_space(3))) unsigned int*)l, 16, 0, 0);
}

__device__ __forceinline__ float wave_sum64(float v) {
#pragma unroll
  for (int off = 32; off > 0; off >>= 1) v += __shfl_xor(v, off);
  return v;
}

__device__ __forceinline__ float block_sum256(float v, float* red) {
  v = wave_sum64(v);
  int w = threadIdx.x >> 6;
  if ((threadIdx.x & 63) == 0) red[w] = v;
  __syncthreads();
  float r = red[0] + red[1] + red[2] + red[3];
  __syncthreads();
  return r;
}

// K0: WqT[h][k] = Wq[k][h]; w2[k] = sum_h Wq[k][h]*bk[h]; c2 = sum_h bq[h]*bk[h]
__global__ void k0_prep(const float* __restrict__ Wq, const float* __restrict__ bk,
                        const float* __restrict__ bq, float* __restrict__ WqT,
                        float* __restrict__ w2c2) {
  __shared__ float red[4];
  int k = blockIdx.x, h = threadIdx.x;
  float v = Wq[k * HH + h];
  WqT[h * HH + k] = v;
  float s = block_sum256(v * bk[h], red);
  if (h == 0) w2c2[k] = s;
  if (k == 0) {
    float s2 = block_sum256(bq[h] * bk[h], red);
    if (h == 0) w2c2[HH] = s2;
  }
}

// K1: per-b small MLP chain -> z[b][:], c1[b]
__global__ __launch_bounds__(256) void k1_perb(
    const float* __restrict__ pro, const float* __restrict__ posx,
    const float* __restrict__ bbox,
    const float* __restrict__ Wqs1, const float* __restrict__ bqs1,
    const float* __restrict__ Wqs2, const float* __restrict__ bqs2,
    const float* __restrict__ Wr1, const float* __restrict__ br1,
    const float* __restrict__ Wr2, const float* __restrict__ br2,
    const float* __restrict__ Wk, const float* __restrict__ WqT,
    const float* __restrict__ bq,
    float* __restrict__ z, float* __restrict__ c1) {
  __shared__ float a0[HH], a1[HH], a2[HH];
  __shared__ float red[4];
  __shared__ float refs[2];
  int b = blockIdx.x, t = threadIdx.x;
  a0[t] = pro[b * HH + t];
  __syncthreads();
  float acc = bqs1[t];
#pragma unroll 8
  for (int k = 0; k < HH; ++k) acc = fmaf(a0[k], Wqs1[k * HH + t], acc);
  a1[t] = fmaxf(acc, 0.f);
  __syncthreads();
  acc = bqs2[t];
#pragma unroll 8
  for (int k = 0; k < HH; ++k) acc = fmaf(a1[k], Wqs2[k * HH + t], acc);
  a2[t] = acc;
  __syncthreads();
  acc = br1[t];
#pragma unroll 8
  for (int k = 0; k < HH; ++k) acc = fmaf(a0[k], Wr1[k * HH + t], acc);
  a1[t] = fmaxf(acc, 0.f);
  __syncthreads();
  float s0 = block_sum256(a1[t] * Wr2[t * 2 + 0], red);
  float s1 = block_sum256(a1[t] * Wr2[t * 2 + 1], red);
  if (t == 0) {
    refs[0] = 1.f / (1.f + __expf(-(s0 + br2[0])));
    refs[1] = 1.f / (1.f + __expf(-(s1 + br2[1])));
  }
  __syncthreads();
  float px = posx[b * HH + t] * a2[t];
  float sc = (t < HH / 2) ? (refs[1] / bbox[b * 4 + 3]) : (refs[0] / bbox[b * 4 + 2]);
  a0[t] = px * sc;
  __syncthreads();
  acc = 0.f;
#pragma unroll 8
  for (int k = 0; k < HH; ++k) acc = fmaf(a0[k], Wk[k * HH + t], acc);
  a1[t] = acc;
  __syncthreads();
  acc = 0.f;
#pragma unroll 8
  for (int k = 0; k < HH; ++k) acc = fmaf(WqT[k * HH + t], a1[k], acc);
  z[b * HH + t] = acc;
  float sc1 = block_sum256(bq[t] * a1[t], red);
  if (t == 0) c1[b] = sc1;
}

// K2: fp[b,s] = posl[s]*(pos_img[s,b]·z[b] + c1[b]) + pos_img[s,b]·w2 + c2
__global__ __launch_bounds__(256) void k2_fp(
    const float* __restrict__ posi, const float* __restrict__ posl,
    const float* __restrict__ z, const float* __restrict__ c1,
    const float* __restrict__ w2c2, float* __restrict__ fp) {
  int b = blockIdx.x, t = threadIdx.x;
  int l = t & 63, w = t >> 6;
  float4 zv = *(const float4*)&z[b * HH + l * 4];
  float4 wv = *(const float4*)&w2c2[l * 4];
  float c1b = c1[b];
  float c2 = w2c2[HH];
  for (int s = w; s < SS; s += 4) {
    float4 pi = *(const float4*)&posi[((size_t)s * BB + b) * HH + l * 4];
    float d1 = pi.x * zv.x + pi.y * zv.y + pi.z * zv.z + pi.w * zv.w;
    float d2 = pi.x * wv.x + pi.y * wv.y + pi.z * wv.z + pi.w * wv.w;
#pragma unroll
    for (int off = 32; off > 0; off >>= 1) {
      d1 += __shfl_xor(d1, off);
      d2 += __shfl_xor(d2, off);
    }
    if (l == 0) fp[b * SS + s] = posl[s] * (d1 + c1b) + d2 + c2;
  }
}

// cast pro -> bf16, padded to MPAD rows (zeros in pad)
__global__ __launch_bounds__(256) void kc_pro(const float* __restrict__ pro,
                                              u16* __restrict__ proh) {
  int tg = blockIdx.x * 256 + threadIdx.x;
  int e0 = tg * 8;  // MPAD*256/8 threads
  int row = e0 >> 8;
  union { u16 u[8]; uint4 v; } pk;
  if (row < BB) {
    float4 v0 = *(const float4*)&pro[e0];
    float4 v1 = *(const float4*)&pro[e0 + 4];
    float vv[8] = {v0.x, v0.y, v0.z, v0.w, v1.x, v1.y, v1.z, v1.w};
#pragma unroll
    for (int i = 0; i < 8; ++i) {
      __hip_bfloat16 hb = __float2bfloat16(vv[i]);
      pk.u[i] = *(u16*)&hb;
    }
  } else {
    pk.v = make_uint4(0, 0, 0, 0);
  }
  *(uint4*)&proh[e0] = pk.v;
}

// transpose+cast Wd (256 x 32768 f32) -> WdT (32768 x 256 bf16)
__global__ __launch_bounds__(256) void kc_wdt(const float* __restrict__ Wd,
                                              u16* __restrict__ wdt) {
  __shared__ float tile[32][33];
  int n0 = blockIdx.x * 32;
  int k0 = blockIdx.y * 32;
  int t = threadIdx.x;
  {
    int kk = t >> 3, nn = (t & 7) * 4;
    float4 v = *(const float4*)&Wd[(size_t)(k0 + kk) * NDP + n0 + nn];
    tile[kk][nn + 0] = v.x;
    tile[kk][nn + 1] = v.y;
    tile[kk][nn + 2] = v.z;
    tile[kk][nn + 3] = v.w;
  }
  __syncthreads();
  {
    int nn = t >> 3, kk = (t & 7) * 4;
    union { u16 u[4]; uint2 v; } pk;
#pragma unroll
    for (int i = 0; i < 4; ++i) {
      __hip_bfloat16 hb = __float2bfloat16(tile[kk + i][nn]);
      pk.u[i] = *(u16*)&hb;
    }
    *(uint2*)&wdt[(size_t)(n0 + nn) * HH + k0 + kk] = pk.v;
  }
}

// transpose+cast Wo (12544 x 256 f32) -> woT (256 x 12544 bf16)
__global__ __launch_bounds__(256) void kc_wot(const float* __restrict__ Wo,
                                              u16* __restrict__ wot) {
  __shared__ float tile[32][33];
  int k0 = blockIdx.x * 32;  // K dim (12544)
  int n0 = blockIdx.y * 32;  // N dim (256)
  int t = threadIdx.x;
  {
    int kk = t >> 3, nn = (t & 7) * 4;
    float4 v = *(const float4*)&Wo[(size_t)(k0 + kk) * HH + n0 + nn];
    tile[kk][nn + 0] = v.x;
    tile[kk][nn + 1] = v.y;
    tile[kk][nn + 2] = v.z;
    tile[kk][nn + 3] = v.w;
  }
  __syncthreads();
  {
    int nn = t >> 3, kk = (t & 7) * 4;
    union { u16 u[4]; uint2 v; } pk;
#pragma unroll
    for (int i = 0; i < 4; ++i) {
      __hip_bfloat16 hb = __float2bfloat16(tile[kk + i][nn]);
      pk.u[i] = *(u16*)&hb;
    }
    *(uint2*)&wot[(size_t)(n0 + nn) * KWO + k0 + kk] = pk.v;
  }
}

// K3: params = proh @ WdT^T + bd via bf16 MFMA. M=4800(pad 4864), N=32768, K=256.
__global__ __launch_bounds__(256) void k3_mfma(const u16* __restrict__ proh,
                                               const u16* __restrict__ wdt,
                                               const float* __restrict__ bd,
                                               u16* __restrict__ params) {
  __shared__ char smem[32768];
  u16* Al = (u16*)smem;           // [128][32] bf16
  u16* Bl = (u16*)(smem + 8192);  // [128][32] bf16 (rows = n)
  const int t = threadIdx.x;
  const int w = t >> 6, l = t & 63;
  const int n0 = blockIdx.x * 128;
  const int m0 = blockIdx.y * 128;
  const int wr = w >> 1, wc = w & 1;
  f32x4 acc[4][4] = {};

  for (int k0 = 0; k0 < HH; k0 += 32) {
#pragma unroll
    for (int i = 0; i < 2; ++i) {
      int c = i * 256 + t;            // chunk id, 16B each
      int r = c >> 2, kq = (c & 3) * 8;
      int wbase = (i * 256 + (w << 6)) * 8;  // elements
      load_lds16(proh + (size_t)(m0 + r) * HH + k0 + kq, Al + wbase);
      load_lds16(wdt + (size_t)(n0 + r) * HH + k0 + kq, Bl + wbase);
    }
    __syncthreads();
    bf16x8 af[4], bfr[4];
#pragma unroll
    for (int mi = 0; mi < 4; ++mi)
      af[mi] = *(const bf16x8*)&Al[(wr * 64 + mi * 16 + (l & 15)) * 32 + (l >> 4) * 8];
#pragma unroll
    for (int ni = 0; ni < 4; ++ni)
      bfr[ni] = *(const bf16x8*)&Bl[(wc * 64 + ni * 16 + (l & 15)) * 32 + (l >> 4) * 8];
#pragma unroll
    for (int mi = 0; mi < 4; ++mi)
#pragma unroll
      for (int ni = 0; ni < 4; ++ni)
        acc[mi][ni] = __builtin_amdgcn_mfma_f32_16x16x32_bf16(af[mi], bfr[ni], acc[mi][ni], 0, 0, 0);
    __syncthreads();
  }
  // epilogue: bias + bf16 -> LDS tile, then coalesced 16B stores
  u16* cb = (u16*)smem;  // [128][128] bf16
#pragma unroll
  for (int ni = 0; ni < 4; ++ni) {
    int col = wc * 64 + ni * 16 + (l & 15);
    float bias = bd[n0 + col];
#pragma unroll
    for (int mi = 0; mi < 4; ++mi) {
#pragma unroll
      for (int j = 0; j < 4; ++j) {
        int row = wr * 64 + mi * 16 + ((l >> 4) << 2) + j;
        __hip_bfloat16 hb = __float2bfloat16(acc[mi][ni][j] + bias);
        cb[row * 128 + col] = *(u16*)&hb;
      }
    }
  }
  __syncthreads();
#pragma unroll
  for (int i = 0; i < 8; ++i) {
    int idx = i * 256 + t;
    int row = idx >> 4, cc = (idx & 15) * 8;
    if (m0 + row < BB)
      *(uint4*)&params[(size_t)(m0 + row) * NDP + n0 + cc] = *(const uint4*)&cb[row * 128 + cc];
  }
}

// K4: per-b dynamic conv: f1 = feat@param1 + fp, LN1+relu, f2 = f1'@param2, LN2+relu -> bf16
__global__ __launch_bounds__(256) void k4_conv(
    const float* __restrict__ roi, const __hip_bfloat16* __restrict__ params,
    const float* __restrict__ fpbuf,
    const float* __restrict__ g1, const float* __restrict__ be1,
    const float* __restrict__ g2, const float* __restrict__ be2,
    __hip_bfloat16* __restrict__ f2ws) {
  int b = blockIdx.x;
  int t = threadIdx.x;
  int l = t & 63, w = t >> 6;
  __shared__ __hip_bfloat16 pbuf[PP];
  __shared__ float dyn[SS * 128];
  {
    const u32* src = (const u32*)(params + (size_t)b * NDP);
    u32* dst = (u32*)pbuf;
    for (int i = 0; i < 32; ++i) dst[t + 256 * i] = src[t + 256 * i];
  }
  float acc[13];
#pragma unroll
  for (int i = 0; i < 13; ++i) acc[i] = 0.f;

  for (int half = 0; half < 2; ++half) {
    const int h0 = half * 128;
    __syncthreads();
    for (int idx = t; idx < SS * 32; idx += 256) {
      int s = idx >> 5, c = (idx & 31) * 4;
      *(float4*)&dyn[s * 128 + c] =
          *(const float4*)&roi[((size_t)s * BB + b) * HH + h0 + c];
    }
    __syncthreads();
    for (int hq = 0; hq < 32; ++hq) {
      int hh = hq * 4;
      float pv0 = bf2f(pbuf[(h0 + hh + 0) * DD + l]);
      float pv1 = bf2f(pbuf[(h0 + hh + 1) * DD + l]);
      float pv2 = bf2f(pbuf[(h0 + hh + 2) * DD + l]);
      float pv3 = bf2f(pbuf[(h0 + hh + 3) * DD + l]);
#pragma unroll
      for (int i = 0; i < 13; ++i) {
        int s = w + 4 * i;
        if (s < SS) {
          float4 fv = *(const float4*)&dyn[s * 128 + hh];
          acc[i] = fmaf(fv.x, pv0, fmaf(fv.y, pv1, fmaf(fv.z, pv2, fmaf(fv.w, pv3, acc[i]))));
        }
      }
    }
  }
  __syncthreads();
  if (t < SS) dyn[SS * DD + t] = fpbuf[b * SS + t];
  __syncthreads();
  {
    float g1v = g1[l], b1v = be1[l];
#pragma unroll
    for (int i = 0; i < 13; ++i) {
      int s = w + 4 * i;
      if (s < SS) {
        float v = acc[i] + dyn[SS * DD + s];
        float m = wave_sum64(v) * (1.f / 64.f);
        float d = v - m;
        float var = wave_sum64(d * d) * (1.f / 64.f);
        float o = fmaxf(fmaf(d * rsqrtf(var + 1e-5f), g1v, b1v), 0.f);
        dyn[s * DD + l] = o;
      }
    }
  }
  __syncthreads();
  {
    const u32* src = (const u32*)(params + (size_t)b * NDP + PP);
    u32* dst = (u32*)pbuf;
    for (int i = 0; i < 32; ++i) dst[t + 256 * i] = src[t + 256 * i];
  }
  __syncthreads();
  float acc2[SS];
#pragma unroll
  for (int s = 0; s < SS; ++s) acc2[s] = 0.f;
  for (int dq = 0; dq < 16; ++dq) {
    int d0 = dq * 4;
    float pv0 = bf2f(pbuf[(d0 + 0) * HH + t]);
    float pv1 = bf2f(pbuf[(d0 + 1) * HH + t]);
    float pv2 = bf2f(pbuf[(d0 + 2) * HH + t]);
    float pv3 = bf2f(pbuf[(d0 + 3) * HH + t]);
#pragma unroll
    for (int s = 0; s < SS; ++s) {
      float4 fv = *(const float4*)&dyn[s * DD + d0];
      acc2[s] = fmaf(fv.x, pv0, fmaf(fv.y, pv1, fmaf(fv.z, pv2, fmaf(fv.w, pv3, acc2[s]))));
    }
  }
  __syncthreads();
  __hip_bfloat16* f2sh = (__hip_bfloat16*)dyn;
#pragma unroll
  for (int s = 0; s < SS; ++s) f2sh[s * HH + t] = __float2bfloat16(acc2[s]);
  __syncthreads();
  {
    float4 g2v = *(const float4*)&g2[l * 4];
    float4 b2v = *(const float4*)&be2[l * 4];
#pragma unroll
    for (int i = 0; i < 13; ++i) {
      int s = w + 4 * i;
      if (s < SS) {
        float v0 = bf2f(f2sh[s * HH + l * 4 + 0]);
        float v1 = bf2f(f2sh[s * HH + l * 4 + 1]);
        float v2 = bf2f(f2sh[s * HH + l * 4 + 2]);
        float v3 = bf2f(f2sh[s * HH + l * 4 + 3]);
        float m = wave_sum64(v0 + v1 + v2 + v3) * (1.f / HH);
        float d0_ = v0 - m, d1_ = v1 - m, d2_ = v2 - m, d3_ = v3 - m;
        float var = wave_sum64(d0_ * d0_ + d1_ * d1_ + d2_ * d2_ + d3_ * d3_) * (1.f / HH);
        float r = rsqrtf(var + 1e-5f);
        float o0 = fmaxf(fmaf(d0_ * r, g2v.x, b2v.x), 0.f);
        float o1 = fmaxf(fmaf(d1_ * r, g2v.y, b2v.y), 0.f);
        float o2 = fmaxf(fmaf(d2_ * r, g2v.z, b2v.z), 0.f);
        float o3 = fmaxf(fmaf(d3_ * r, g2v.w, b2v.w), 0.f);
        union { u16 u[4]; uint2 v2_; } pk;
        __hip_bfloat16 hb;
        hb = __float2bfloat16(o0); pk.u[0] = *(u16*)&hb;
        hb = __float2bfloat16(o1); pk.u[1] = *(u16*)&hb;
        hb = __float2bfloat16(o2); pk.u[2] = *(u16*)&hb;
        hb = __float2bfloat16(o3); pk.u[3] = *(u16*)&hb;
        *(uint2*)&f2ws[(size_t)b * KWO + s * HH + l * 4] = pk.v2_;
      }
    }
  }
}

// K5: partial[sk][m][n] = f2ws[m, kchunk] @ woT[n, kchunk]^T  via bf16 MFMA, split-K.
// BM=64, BN=128, BK=32. grid (SK, 75, 2).
__global__ __launch_bounds__(256) void k5_mfma(const u16* __restrict__ f2,
                                               const u16* __restrict__ wot,
                                               float* __restrict__ part) {
  __shared__ char smem[12288];
  u16* Al = (u16*)smem;           // [64][32] bf16
  u16* Bl = (u16*)(smem + 4096);  // [128][32] bf16 (rows = n)
  const int t = threadIdx.x;
  const int w = t >> 6, l = t & 63;
  const int sk = blockIdx.x;
  const int m0 = blockIdx.y * 64;
  const int n0 = blockIdx.z * 128;
  const size_t kbase = (size_t)sk * KCH;
  const int wr = w >> 1, wc = w & 1;  // wave: 32 rows x 64 cols
  f32x4 acc[2][4] = {};

  for (int k0 = 0; k0 < KCH; k0 += 32) {
    {
      // A: 64 rows x 32 k = 256 chunks of 16B, one per thread
      int r = t >> 2, kq = (t & 3) * 8;
      int wbase = (w << 6) * 8;
      load_lds16(f2 + (size_t)(m0 + r) * KWO + kbase + k0 + kq, Al + wbase);
    }
#pragma unroll
    for (int i = 0; i < 2; ++i) {
      // B: 128 rows x 32 k = 512 chunks
      int c = i * 256 + t;
      int r = c >> 2, kq = (c & 3) * 8;
      int wbase = (i * 256 + (w << 6)) * 8;
      load_lds16(wot + (size_t)(n0 + r) * KWO + kbase + k0 + kq, Bl + wbase);
    }
    __syncthreads();
    bf16x8 af[2], bfr[4];
#pragma unroll
    for (int mi = 0; mi < 2; ++mi)
      af[mi] = *(const bf16x8*)&Al[(wr * 32 + mi * 16 + (l & 15)) * 32 + (l >> 4) * 8];
#pragma unroll
    for (int ni = 0; ni < 4; ++ni)
      bfr[ni] = *(const bf16x8*)&Bl[(wc * 64 + ni * 16 + (l & 15)) * 32 + (l >> 4) * 8];
#pragma unroll
    for (int mi = 0; mi < 2; ++mi)
#pragma unroll
      for (int ni = 0; ni < 4; ++ni)
        acc[mi][ni] = __builtin_amdgcn_mfma_f32_16x16x32_bf16(af[mi], bfr[ni], acc[mi][ni], 0, 0, 0);
    __syncthreads();
  }
  // write fp32 partials: lane-contiguous over 16 cols
#pragma unroll
  for (int mi = 0; mi < 2; ++mi) {
#pragma unroll
    for (int j = 0; j < 4; ++j) {
      int m = m0 + wr * 32 + mi * 16 + ((l >> 4) << 2) + j;
#pragma unroll
      for (int ni = 0; ni < 4; ++ni) {
        int n = n0 + wc * 64 + ni * 16 + (l & 15);
        part[((size_t)sk * BB + m) * HH + n] = acc[mi][ni][j];
      }
    }
  }
}

// K5R: reduce partials + bias, LN3 + relu -> out
__global__ __launch_bounds__(256) void k5r_ln3(
    const float* __restrict__ part, const float* __restrict__ bo,
    const float* __restrict__ g3, const float* __restrict__ be3,
    float* __restrict__ out) {
  __shared__ float red[4];
  int b = blockIdx.x, t = threadIdx.x;
  float v = bo[t];
#pragma unroll
  for (int sk = 0; sk < SK; ++sk) v += part[((size_t)sk * BB + b) * HH + t];
  float m = block_sum256(v, red) * (1.f / HH);
  float d = v - m;
  float var = block_sum256(d * d, red) * (1.f / HH);
  out[b * HH + t] = fmaxf(fmaf(d * rsqrtf(var + 1e-5f), g3[t], be3[t]), 0.f);
}

extern "C" void kernel_launch(void* const* d_in, const int* in_sizes, int n_in,
                              void* d_out, int out_size, void* d_ws, size_t ws_size,
                              hipStream_t stream) {
  const float* pro  = (const float*)d_in[0];
  const float* roi  = (const float*)d_in[1];
  const float* posx = (const float*)d_in[2];
  const float* posi = (const float*)d_in[3];
  const float* posl = (const float*)d_in[4];
  const float* bbox = (const float*)d_in[5];
  const float* Wd   = (const float*)d_in[6];
  const float* bd   = (const float*)d_in[7];
  const float* Wqs1 = (const float*)d_in[8];
  const float* bqs1 = (const float*)d_in[9];
  const float* Wqs2 = (const float*)d_in[10];
  const float* bqs2 = (const float*)d_in[11];
  const float* Wr1  = (const float*)d_in[12];
  const float* br1  = (const float*)d_in[13];
  const float* Wr2  = (const float*)d_in[14];
  const float* br2  = (const float*)d_in[15];
  const float* Wq   = (const float*)d_in[16];
  const float* bq   = (const float*)d_in[17];
  const float* Wk   = (const float*)d_in[18];
  const float* bk   = (const float*)d_in[19];
  const float* g1   = (const float*)d_in[20];
  const float* be1  = (const float*)d_in[21];
  const float* g2   = (const float*)d_in[22];
  const float* be2  = (const float*)d_in[23];
  const float* g3   = (const float*)d_in[24];
  const float* be3  = (const float*)d_in[25];
  const float* Wo   = (const float*)d_in[26];
  const float* bo   = (const float*)d_in[27];

  // ws layout (bytes):
  //   params  @ 0          (314572800)  -- dead after k4; part aliases it
  //   part    @ 0          (39321600, SK*BB*HH*4) -- written by k5, read by k5r
  //   f2ws    @ 314572800  (120422400)
  //   proh    @ 314572800  (2490368, alias f2ws; dead after k3)
  //   wdt     @ 317063168  (16777216, alias f2ws; dead after k3)
  //   woT     @ 434995200  (6422528, overlays z+obuf region; z dead after k2)
  //   fp      @ 444825600  (940800)
  //   c1      @ 445766400  (19200)
  //   WqT     @ 445785600  (262144)
  //   w2c2    @ 446047744  (1040)
  //   z       @ 434995200  (4915200, dead after k2 -> woT overlays)
  char* ws = (char*)d_ws;
  __hip_bfloat16* params = (__hip_bfloat16*)(ws + 0ull);
  float* part = (float*)(ws + 0ull);
  __hip_bfloat16* f2ws   = (__hip_bfloat16*)(ws + 314572800ull);
  u16* proh = (u16*)(ws + 314572800ull);
  u16* wdt  = (u16*)(ws + 317063168ull);
  float* z    = (float*)(ws + 434995200ull);
  u16* wot  = (u16*)(ws + 434995200ull);
  float* fp   = (float*)(ws + 444825600ull);
  float* c1   = (float*)(ws + 445766400ull);
  float* WqT  = (float*)(ws + 445785600ull);
  float* w2c2 = (float*)(ws + 446047744ull);

  k0_prep<<<dim3(256), dim3(256), 0, stream>>>(Wq, bk, bq, WqT, w2c2);
  k1_perb<<<dim3(BB), dim3(256), 0, stream>>>(pro, posx, bbox, Wqs1, bqs1, Wqs2, bqs2,
                                              Wr1, br1, Wr2, br2, Wk, WqT, bq, z, c1);
  k2_fp<<<dim3(BB), dim3(256), 0, stream>>>(posi, posl, z, c1, w2c2, fp);
  // z dead from here; woT overlays it
  kc_wot<<<dim3(KWO / 32, HH / 32), dim3(256), 0, stream>>>(Wo, wot);
  kc_pro<<<dim3(MPAD * HH / 8 / 256), dim3(256), 0, stream>>>(pro, proh);
  kc_wdt<<<dim3(NDP / 32, HH / 32), dim3(256), 0, stream>>>(Wd, wdt);
  k3_mfma<<<dim3(NDP / 128, MPAD / 128), dim3(256), 0, stream>>>(proh, wdt, bd,
                                                                 (u16*)params);
  k4_conv<<<dim3(BB), dim3(256), 0, stream>>>(roi, params, fp, g1, be1, g2, be2, f2ws);
  // params dead from here; part overlays it
  k5_mfma<<<dim3(SK, BB / 64, HH / 128), dim3(256), 0, stream>>>((const u16*)f2ws, wot, part);
  k5r_ln3<<<dim3(BB), dim3(256), 0, stream>>>(part, bo, g3, be3, (float*)d_out);
}

// Round 5
// 734.466 us; speedup vs baseline: 3.4223x; 1.6039x over previous
//
#include <hip/hip_runtime.h>
#include <hip/hip_bf16.h>

#define HH 256
#define DD 64
#define SS 49
#define BB 4800
#define PP 16384
#define NDP 32768
#define KWO 12544  // S*H
#define MPAD 4864  // BB padded to 128
#define SK 8       // split-K factor for K5
#define KCH 1568   // KWO / SK = 49 * 32

typedef unsigned int u32;
typedef unsigned short u16;
typedef __attribute__((ext_vector_type(8))) short bf16x8;
typedef __attribute__((ext_vector_type(4))) float f32x4;

__device__ __forceinline__ float bf2f(__hip_bfloat16 h) { return __bfloat162float(h); }

__device__ __forceinline__ void load_lds16(const void* g, void* l) {
  __builtin_amdgcn_global_load_lds(
      (const __attribute__((address_space(1))) unsigned int*)g,
      (__attribute__((address_space(3))) unsigned int*)l, 16, 0, 0);
}

// permutation of the params N-dim: param1 (n=h*64+d) -> [d][h]; param2 -> [h][d]
__device__ __forceinline__ int nperm(int n) {
  if (n < PP) { int h = n >> 6, d = n & 63; return d * HH + h; }
  int r = n - PP; int d = r >> 8, h = r & 255; return PP + h * DD + d;
}

__device__ __forceinline__ float wave_sum64(float v) {
#pragma unroll
  for (int off = 32; off > 0; off >>= 1) v += __shfl_xor(v, off);
  return v;
}

__device__ __forceinline__ float block_sum256(float v, float* red) {
  v = wave_sum64(v);
  int w = threadIdx.x >> 6;
  if ((threadIdx.x & 63) == 0) red[w] = v;
  __syncthreads();
  float r = red[0] + red[1] + red[2] + red[3];
  __syncthreads();
  return r;
}

// K0: WqT[h][k] = Wq[k][h]; w2[k] = sum_h Wq[k][h]*bk[h]; c2 = sum_h bq[h]*bk[h]
__global__ void k0_prep(const float* __restrict__ Wq, const float* __restrict__ bk,
                        const float* __restrict__ bq, float* __restrict__ WqT,
                        float* __restrict__ w2c2) {
  __shared__ float red[4];
  int k = blockIdx.x, h = threadIdx.x;
  float v = Wq[k * HH + h];
  WqT[h * HH + k] = v;
  float s = block_sum256(v * bk[h], red);
  if (h == 0) w2c2[k] = s;
  if (k == 0) {
    float s2 = block_sum256(bq[h] * bk[h], red);
    if (h == 0) w2c2[HH] = s2;
  }
}

// K1: per-b small MLP chain -> z[b][:], c1[b]
__global__ __launch_bounds__(256) void k1_perb(
    const float* __restrict__ pro, const float* __restrict__ posx,
    const float* __restrict__ bbox,
    const float* __restrict__ Wqs1, const float* __restrict__ bqs1,
    const float* __restrict__ Wqs2, const float* __restrict__ bqs2,
    const float* __restrict__ Wr1, const float* __restrict__ br1,
    const float* __restrict__ Wr2, const float* __restrict__ br2,
    const float* __restrict__ Wk, const float* __restrict__ WqT,
    const float* __restrict__ bq,
    float* __restrict__ z, float* __restrict__ c1) {
  __shared__ float a0[HH], a1[HH], a2[HH];
  __shared__ float red[4];
  __shared__ float refs[2];
  int b = blockIdx.x, t = threadIdx.x;
  a0[t] = pro[b * HH + t];
  __syncthreads();
  float acc = bqs1[t];
#pragma unroll 8
  for (int k = 0; k < HH; ++k) acc = fmaf(a0[k], Wqs1[k * HH + t], acc);
  a1[t] = fmaxf(acc, 0.f);
  __syncthreads();
  acc = bqs2[t];
#pragma unroll 8
  for (int k = 0; k < HH; ++k) acc = fmaf(a1[k], Wqs2[k * HH + t], acc);
  a2[t] = acc;
  __syncthreads();
  acc = br1[t];
#pragma unroll 8
  for (int k = 0; k < HH; ++k) acc = fmaf(a0[k], Wr1[k * HH + t], acc);
  a1[t] = fmaxf(acc, 0.f);
  __syncthreads();
  float s0 = block_sum256(a1[t] * Wr2[t * 2 + 0], red);
  float s1 = block_sum256(a1[t] * Wr2[t * 2 + 1], red);
  if (t == 0) {
    refs[0] = 1.f / (1.f + __expf(-(s0 + br2[0])));
    refs[1] = 1.f / (1.f + __expf(-(s1 + br2[1])));
  }
  __syncthreads();
  float px = posx[b * HH + t] * a2[t];
  float sc = (t < HH / 2) ? (refs[1] / bbox[b * 4 + 3]) : (refs[0] / bbox[b * 4 + 2]);
  a0[t] = px * sc;
  __syncthreads();
  acc = 0.f;
#pragma unroll 8
  for (int k = 0; k < HH; ++k) acc = fmaf(a0[k], Wk[k * HH + t], acc);
  a1[t] = acc;
  __syncthreads();
  acc = 0.f;
#pragma unroll 8
  for (int k = 0; k < HH; ++k) acc = fmaf(WqT[k * HH + t], a1[k], acc);
  z[b * HH + t] = acc;
  float sc1 = block_sum256(bq[t] * a1[t], red);
  if (t == 0) c1[b] = sc1;
}

// K2: fp[b,s] = posl[s]*(pos_img[s,b]·z[b] + c1[b]) + pos_img[s,b]·w2 + c2
__global__ __launch_bounds__(256) void k2_fp(
    const float* __restrict__ posi, const float* __restrict__ posl,
    const float* __restrict__ z, const float* __restrict__ c1,
    const float* __restrict__ w2c2, float* __restrict__ fp) {
  int b = blockIdx.x, t = threadIdx.x;
  int l = t & 63, w = t >> 6;
  float4 zv = *(const float4*)&z[b * HH + l * 4];
  float4 wv = *(const float4*)&w2c2[l * 4];
  float c1b = c1[b];
  float c2 = w2c2[HH];
  for (int s = w; s < SS; s += 4) {
    float4 pi = *(const float4*)&posi[((size_t)s * BB + b) * HH + l * 4];
    float d1 = pi.x * zv.x + pi.y * zv.y + pi.z * zv.z + pi.w * zv.w;
    float d2 = pi.x * wv.x + pi.y * wv.y + pi.z * wv.z + pi.w * wv.w;
#pragma unroll
    for (int off = 32; off > 0; off >>= 1) {
      d1 += __shfl_xor(d1, off);
      d2 += __shfl_xor(d2, off);
    }
    if (l == 0) fp[b * SS + s] = posl[s] * (d1 + c1b) + d2 + c2;
  }
}

// cast pro -> bf16, padded to MPAD rows (zeros in pad)
__global__ __launch_bounds__(256) void kc_pro(const float* __restrict__ pro,
                                              u16* __restrict__ proh) {
  int tg = blockIdx.x * 256 + threadIdx.x;
  int e0 = tg * 8;  // MPAD*256/8 threads
  int row = e0 >> 8;
  union { u16 u[8]; uint4 v; } pk;
  if (row < BB) {
    float4 v0 = *(const float4*)&pro[e0];
    float4 v1 = *(const float4*)&pro[e0 + 4];
    float vv[8] = {v0.x, v0.y, v0.z, v0.w, v1.x, v1.y, v1.z, v1.w};
#pragma unroll
    for (int i = 0; i < 8; ++i) {
      __hip_bfloat16 hb = __float2bfloat16(vv[i]);
      pk.u[i] = *(u16*)&hb;
    }
  } else {
    pk.v = make_uint4(0, 0, 0, 0);
  }
  *(uint4*)&proh[e0] = pk.v;
}

// transpose+cast Wd (256 x 32768 f32) -> wdt[nperm(n)][k] bf16
__global__ __launch_bounds__(256) void kc_wdt(const float* __restrict__ Wd,
                                              u16* __restrict__ wdt) {
  __shared__ float tile[32][33];
  int n0 = blockIdx.x * 32;
  int k0 = blockIdx.y * 32;
  int t = threadIdx.x;
  {
    int kk = t >> 3, nn = (t & 7) * 4;
    float4 v = *(const float4*)&Wd[(size_t)(k0 + kk) * NDP + n0 + nn];
    tile[kk][nn + 0] = v.x;
    tile[kk][nn + 1] = v.y;
    tile[kk][nn + 2] = v.z;
    tile[kk][nn + 3] = v.w;
  }
  __syncthreads();
  {
    int nn = t >> 3, kk = (t & 7) * 4;
    union { u16 u[4]; uint2 v; } pk;
#pragma unroll
    for (int i = 0; i < 4; ++i) {
      __hip_bfloat16 hb = __float2bfloat16(tile[kk + i][nn]);
      pk.u[i] = *(u16*)&hb;
    }
    int np = nperm(n0 + nn);
    *(uint2*)&wdt[(size_t)np * HH + k0 + kk] = pk.v;
  }
}

// bdp[nperm(n)] = bd[n]
__global__ void kc_bdp(const float* __restrict__ bd, float* __restrict__ bdp) {
  int n = blockIdx.x * 256 + threadIdx.x;
  bdp[nperm(n)] = bd[n];
}

// transpose+cast Wo (12544 x 256 f32) -> woT (256 x 12544 bf16)
__global__ __launch_bounds__(256) void kc_wot(const float* __restrict__ Wo,
                                              u16* __restrict__ wot) {
  __shared__ float tile[32][33];
  int k0 = blockIdx.x * 32;  // K dim (12544)
  int n0 = blockIdx.y * 32;  // N dim (256)
  int t = threadIdx.x;
  {
    int kk = t >> 3, nn = (t & 7) * 4;
    float4 v = *(const float4*)&Wo[(size_t)(k0 + kk) * HH + n0 + nn];
    tile[kk][nn + 0] = v.x;
    tile[kk][nn + 1] = v.y;
    tile[kk][nn + 2] = v.z;
    tile[kk][nn + 3] = v.w;
  }
  __syncthreads();
  {
    int nn = t >> 3, kk = (t & 7) * 4;
    union { u16 u[4]; uint2 v; } pk;
#pragma unroll
    for (int i = 0; i < 4; ++i) {
      __hip_bfloat16 hb = __float2bfloat16(tile[kk + i][nn]);
      pk.u[i] = *(u16*)&hb;
    }
    *(uint2*)&wot[(size_t)(n0 + nn) * KWO + k0 + kk] = pk.v;
  }
}

// K3: params = proh @ wdt^T + bdp via bf16 MFMA. M=4800(pad 4864), N=32768, K=256.
__global__ __launch_bounds__(256) void k3_mfma(const u16* __restrict__ proh,
                                               const u16* __restrict__ wdt,
                                               const float* __restrict__ bdp,
                                               u16* __restrict__ params) {
  __shared__ char smem[32768];
  u16* Al = (u16*)smem;           // [128][32] bf16
  u16* Bl = (u16*)(smem + 8192);  // [128][32] bf16 (rows = n)
  const int t = threadIdx.x;
  const int w = t >> 6, l = t & 63;
  const int n0 = blockIdx.x * 128;
  const int m0 = blockIdx.y * 128;
  const int wr = w >> 1, wc = w & 1;
  f32x4 acc[4][4] = {};

  for (int k0 = 0; k0 < HH; k0 += 32) {
#pragma unroll
    for (int i = 0; i < 2; ++i) {
      int c = i * 256 + t;            // chunk id, 16B each
      int r = c >> 2, kq = (c & 3) * 8;
      int wbase = (i * 256 + (w << 6)) * 8;  // elements
      load_lds16(proh + (size_t)(m0 + r) * HH + k0 + kq, Al + wbase);
      load_lds16(wdt + (size_t)(n0 + r) * HH + k0 + kq, Bl + wbase);
    }
    __syncthreads();
    bf16x8 af[4], bfr[4];
#pragma unroll
    for (int mi = 0; mi < 4; ++mi)
      af[mi] = *(const bf16x8*)&Al[(wr * 64 + mi * 16 + (l & 15)) * 32 + (l >> 4) * 8];
#pragma unroll
    for (int ni = 0; ni < 4; ++ni)
      bfr[ni] = *(const bf16x8*)&Bl[(wc * 64 + ni * 16 + (l & 15)) * 32 + (l >> 4) * 8];
#pragma unroll
    for (int mi = 0; mi < 4; ++mi)
#pragma unroll
      for (int ni = 0; ni < 4; ++ni)
        acc[mi][ni] = __builtin_amdgcn_mfma_f32_16x16x32_bf16(af[mi], bfr[ni], acc[mi][ni], 0, 0, 0);
    __syncthreads();
  }
  u16* cb = (u16*)smem;  // [128][128] bf16
#pragma unroll
  for (int ni = 0; ni < 4; ++ni) {
    int col = wc * 64 + ni * 16 + (l & 15);
    float bias = bdp[n0 + col];
#pragma unroll
    for (int mi = 0; mi < 4; ++mi) {
#pragma unroll
      for (int j = 0; j < 4; ++j) {
        int row = wr * 64 + mi * 16 + ((l >> 4) << 2) + j;
        __hip_bfloat16 hb = __float2bfloat16(acc[mi][ni][j] + bias);
        cb[row * 128 + col] = *(u16*)&hb;
      }
    }
  }
  __syncthreads();
#pragma unroll
  for (int i = 0; i < 8; ++i) {
    int idx = i * 256 + t;
    int row = idx >> 4, cc = (idx & 15) * 8;
    if (m0 + row < BB)
      *(uint4*)&params[(size_t)(m0 + row) * NDP + n0 + cc] = *(const uint4*)&cb[row * 128 + cc];
  }
}

// K4: per-b dynamic conv via MFMA. params permuted: param1T [d][h], param2T [h][d].
// f1(64x64,K=256) -> LN1+relu -> f2(64x256,K=64) -> LN2+relu -> f2ws bf16
__global__ __launch_bounds__(256) void k4_mfma(
    const float* __restrict__ roi, const u16* __restrict__ params,
    const float* __restrict__ fpbuf,
    const float* __restrict__ g1, const float* __restrict__ be1,
    const float* __restrict__ g2, const float* __restrict__ be2,
    u16* __restrict__ f2ws) {
  __shared__ u16 bufA[16384];   // featL [64][256] swz; later p2L [256][64] swz
  __shared__ u16 bufP1[16384];  // p1L [64][256] swz
  __shared__ u16 f1L[4096];     // [64][64] swz
  __shared__ float fpL[64];
  __shared__ float g1L[64], b1L[64], g2L[256], b2L[256];

  const int b = blockIdx.x;
  const int t = threadIdx.x;
  const int w = t >> 6, l = t & 63;
  const int lg = l >> 4, lr = l & 15;
  const int swz = (lr & 7) << 4;  // per-lane read swizzle (row&7 == lr&7 for all frags)

  // stage p1 (param1T [64][256]) via global_load_lds, source pre-swizzled
#pragma unroll
  for (int i = 0; i < 8; ++i) {
    int c = i * 256 + t;
    int a = c * 16;            // linear LDS byte
    int row = a >> 9;          // 512B rows
    int x0 = a & 511;
    int src = b * NDP + row * HH + ((x0 ^ ((row & 7) << 4)) >> 1);
    load_lds16(params + src, (char*)bufP1 + (size_t)(i * 256 + (w << 6)) * 16);
  }
  // p2 (param2T [256][64]) -> regs, linear
  uint4 p2r[8];
#pragma unroll
  for (int i = 0; i < 8; ++i) {
    int c = i * 256 + t;
    p2r[i] = *(const uint4*)&params[(size_t)b * NDP + PP + c * 8];
  }
  // featL: fp32 -> bf16, swizzled ds_write. [64][256], rows >= SS zeroed.
#pragma unroll
  for (int i = 0; i < 16; ++i) {
    int idx = i * 256 + t;          // float4-unit over 64x64
    int row = idx >> 6, c4 = (idx & 63) << 2;
    union { u16 u[4]; unsigned long long v; } pk;
    if (row < SS) {
      float4 v = *(const float4*)&roi[((size_t)row * BB + b) * HH + c4];
      __hip_bfloat16 h0 = __float2bfloat16(v.x), h1 = __float2bfloat16(v.y);
      __hip_bfloat16 h2 = __float2bfloat16(v.z), h3 = __float2bfloat16(v.w);
      pk.u[0] = *(u16*)&h0; pk.u[1] = *(u16*)&h1;
      pk.u[2] = *(u16*)&h2; pk.u[3] = *(u16*)&h3;
    } else {
      pk.v = 0ull;
    }
    int ab = (row << 9) + (((c4 << 1)) ^ ((row & 7) << 4));
    *(unsigned long long*)((char*)bufA + ab) = pk.v;
  }
  if (t < 64) {
    fpL[t] = (t < SS) ? fpbuf[b * SS + t] : 0.f;
    g1L[t] = g1[t];
    b1L[t] = be1[t];
  }
  g2L[t] = g2[t];
  b2L[t] = be2[t];
  __syncthreads();

  // f1 = feat @ param1: M=64 (wave w owns rows w*16..+16), N=64, K=256
  f32x4 acc1[4] = {};
#pragma unroll
  for (int k0 = 0; k0 < HH; k0 += 32) {
    int colb = ((k0 + (lg << 3)) << 1) ^ swz;
    const bf16x8 af = *(const bf16x8*)((const char*)bufA + ((w * 16 + lr) << 9) + colb);
    bf16x8 bfr[4];
#pragma unroll
    for (int ni = 0; ni < 4; ++ni)
      bfr[ni] = *(const bf16x8*)((const char*)bufP1 + ((ni * 16 + lr) << 9) + colb);
#pragma unroll
    for (int ni = 0; ni < 4; ++ni)
      acc1[ni] = __builtin_amdgcn_mfma_f32_16x16x32_bf16(af, bfr[ni], acc1[ni], 0, 0, 0);
  }
  __syncthreads();  // featL dead, bufA rewritten below

  // p2 regs -> bufA as [256][64] swizzled
#pragma unroll
  for (int i = 0; i < 8; ++i) {
    int c = i * 256 + t;
    int a = c * 16;
    int row = a >> 7;          // 128B rows
    int x0 = a & 127;
    *(uint4*)((char*)bufA + (row << 7) + (x0 ^ ((row & 7) << 4))) = p2r[i];
  }

  // LN1 + relu -> f1L bf16 (C frag: row=(lg*4+j), col=ni*16+lr)
#pragma unroll
  for (int j = 0; j < 4; ++j) {
    int s = w * 16 + (lg << 2) + j;
    float fpv = fpL[s];
    float x[4], sum = 0.f, sq = 0.f;
#pragma unroll
    for (int ni = 0; ni < 4; ++ni) {
      x[ni] = acc1[ni][j] + fpv;
      sum += x[ni];
      sq += x[ni] * x[ni];
    }
#pragma unroll
    for (int off = 1; off < 16; off <<= 1) {
      sum += __shfl_xor(sum, off);
      sq += __shfl_xor(sq, off);
    }
    float m = sum * (1.f / 64.f);
    float rs = rsqrtf(sq * (1.f / 64.f) - m * m + 1e-5f);
#pragma unroll
    for (int ni = 0; ni < 4; ++ni) {
      int d = ni * 16 + lr;
      float o = fmaxf((x[ni] - m) * rs * g1L[d] + b1L[d], 0.f);
      __hip_bfloat16 hb = __float2bfloat16(o);
      *(u16*)((char*)f1L + (s << 7) + ((d << 1) ^ ((s & 7) << 4))) = *(u16*)&hb;
    }
  }
  __syncthreads();

  // f2 = f1 @ param2: M=64, N=256, K=64
  f32x4 acc2[16] = {};
#pragma unroll
  for (int k0 = 0; k0 < 64; k0 += 32) {
    int colb = ((k0 + (lg << 3)) << 1) ^ swz;
    const bf16x8 af = *(const bf16x8*)((const char*)f1L + ((w * 16 + lr) << 7) + colb);
#pragma unroll
    for (int ni = 0; ni < 16; ++ni) {
      const bf16x8 bfr = *(const bf16x8*)((const char*)bufA + ((ni * 16 + lr) << 7) + colb);
      acc2[ni] = __builtin_amdgcn_mfma_f32_16x16x32_bf16(af, bfr, acc2[ni], 0, 0, 0);
    }
  }

  // LN2 + relu -> f2ws
#pragma unroll
  for (int j = 0; j < 4; ++j) {
    int s = w * 16 + (lg << 2) + j;
    float sum = 0.f, sq = 0.f;
#pragma unroll
    for (int ni = 0; ni < 16; ++ni) {
      float v = acc2[ni][j];
      sum += v;
      sq += v * v;
    }
#pragma unroll
    for (int off = 1; off < 16; off <<= 1) {
      sum += __shfl_xor(sum, off);
      sq += __shfl_xor(sq, off);
    }
    float m = sum * (1.f / 256.f);
    float rs = rsqrtf(sq * (1.f / 256.f) - m * m + 1e-5f);
    if (s < SS) {
#pragma unroll
      for (int ni = 0; ni < 16; ++ni) {
        int h = ni * 16 + lr;
        float o = fmaxf((acc2[ni][j] - m) * rs * g2L[h] + b2L[h], 0.f);
        __hip_bfloat16 hb = __float2bfloat16(o);
        f2ws[(size_t)b * KWO + s * HH + h] = *(u16*)&hb;
      }
    }
  }
}

// K5: partial[sk][m][n] = f2ws[m, kchunk] @ woT[n, kchunk]^T, split-K bf16 MFMA.
__global__ __launch_bounds__(256) void k5_mfma(const u16* __restrict__ f2,
                                               const u16* __restrict__ wot,
                                               float* __restrict__ part) {
  __shared__ char smem[12288];
  u16* Al = (u16*)smem;           // [64][32] bf16
  u16* Bl = (u16*)(smem + 4096);  // [128][32] bf16 (rows = n)
  const int t = threadIdx.x;
  const int w = t >> 6, l = t & 63;
  const int sk = blockIdx.x;
  const int m0 = blockIdx.y * 64;
  const int n0 = blockIdx.z * 128;
  const size_t kbase = (size_t)sk * KCH;
  const int wr = w >> 1, wc = w & 1;
  f32x4 acc[2][4] = {};

  for (int k0 = 0; k0 < KCH; k0 += 32) {
    {
      int r = t >> 2, kq = (t & 3) * 8;
      int wbase = (w << 6) * 8;
      load_lds16(f2 + (size_t)(m0 + r) * KWO + kbase + k0 + kq, Al + wbase);
    }
#pragma unroll
    for (int i = 0; i < 2; ++i) {
      int c = i * 256 + t;
      int r = c >> 2, kq = (c & 3) * 8;
      int wbase = (i * 256 + (w << 6)) * 8;
      load_lds16(wot + (size_t)(n0 + r) * KWO + kbase + k0 + kq, Bl + wbase);
    }
    __syncthreads();
    bf16x8 af[2], bfr[4];
#pragma unroll
    for (int mi = 0; mi < 2; ++mi)
      af[mi] = *(const bf16x8*)&Al[(wr * 32 + mi * 16 + (l & 15)) * 32 + (l >> 4) * 8];
#pragma unroll
    for (int ni = 0; ni < 4; ++ni)
      bfr[ni] = *(const bf16x8*)&Bl[(wc * 64 + ni * 16 + (l & 15)) * 32 + (l >> 4) * 8];
#pragma unroll
    for (int mi = 0; mi < 2; ++mi)
#pragma unroll
      for (int ni = 0; ni < 4; ++ni)
        acc[mi][ni] = __builtin_amdgcn_mfma_f32_16x16x32_bf16(af[mi], bfr[ni], acc[mi][ni], 0, 0, 0);
    __syncthreads();
  }
#pragma unroll
  for (int mi = 0; mi < 2; ++mi) {
#pragma unroll
    for (int j = 0; j < 4; ++j) {
      int m = m0 + wr * 32 + mi * 16 + ((l >> 4) << 2) + j;
#pragma unroll
      for (int ni = 0; ni < 4; ++ni) {
        int n = n0 + wc * 64 + ni * 16 + (l & 15);
        part[((size_t)sk * BB + m) * HH + n] = acc[mi][ni][j];
      }
    }
  }
}

// K5R: reduce partials + bias, LN3 + relu -> out
__global__ __launch_bounds__(256) void k5r_ln3(
    const float* __restrict__ part, const float* __restrict__ bo,
    const float* __restrict__ g3, const float* __restrict__ be3,
    float* __restrict__ out) {
  __shared__ float red[4];
  int b = blockIdx.x, t = threadIdx.x;
  float v = bo[t];
#pragma unroll
  for (int sk = 0; sk < SK; ++sk) v += part[((size_t)sk * BB + b) * HH + t];
  float m = block_sum256(v, red) * (1.f / HH);
  float d = v - m;
  float var = block_sum256(d * d, red) * (1.f / HH);
  out[b * HH + t] = fmaxf(fmaf(d * rsqrtf(var + 1e-5f), g3[t], be3[t]), 0.f);
}

extern "C" void kernel_launch(void* const* d_in, const int* in_sizes, int n_in,
                              void* d_out, int out_size, void* d_ws, size_t ws_size,
                              hipStream_t stream) {
  const float* pro  = (const float*)d_in[0];
  const float* roi  = (const float*)d_in[1];
  const float* posx = (const float*)d_in[2];
  const float* posi = (const float*)d_in[3];
  const float* posl = (const float*)d_in[4];
  const float* bbox = (const float*)d_in[5];
  const float* Wd   = (const float*)d_in[6];
  const float* bd   = (const float*)d_in[7];
  const float* Wqs1 = (const float*)d_in[8];
  const float* bqs1 = (const float*)d_in[9];
  const float* Wqs2 = (const float*)d_in[10];
  const float* bqs2 = (const float*)d_in[11];
  const float* Wr1  = (const float*)d_in[12];
  const float* br1  = (const float*)d_in[13];
  const float* Wr2  = (const float*)d_in[14];
  const float* br2  = (const float*)d_in[15];
  const float* Wq   = (const float*)d_in[16];
  const float* bq   = (const float*)d_in[17];
  const float* Wk   = (const float*)d_in[18];
  const float* bk   = (const float*)d_in[19];
  const float* g1   = (const float*)d_in[20];
  const float* be1  = (const float*)d_in[21];
  const float* g2   = (const float*)d_in[22];
  const float* be2  = (const float*)d_in[23];
  const float* g3   = (const float*)d_in[24];
  const float* be3  = (const float*)d_in[25];
  const float* Wo   = (const float*)d_in[26];
  const float* bo   = (const float*)d_in[27];

  // ws layout (bytes):
  //   params/part @ 0          (314572800 / 39321600)
  //   f2ws        @ 314572800  (120422400); proh/wdt alias (dead after k3)
  //   wot         @ 434995200  (6422528, overlays z; z dead after k2)
  //   bdp         @ 441417728  (131072)
  //   fp          @ 444825600  (940800)
  //   c1          @ 445766400  (19200)
  //   WqT         @ 445785600  (262144)
  //   w2c2        @ 446047744  (1040)
  char* ws = (char*)d_ws;
  u16* params = (u16*)(ws + 0ull);
  float* part = (float*)(ws + 0ull);
  u16* f2ws   = (u16*)(ws + 314572800ull);
  u16* proh   = (u16*)(ws + 314572800ull);
  u16* wdt    = (u16*)(ws + 317063168ull);
  float* z    = (float*)(ws + 434995200ull);
  u16* wot    = (u16*)(ws + 434995200ull);
  float* bdp  = (float*)(ws + 441417728ull);
  float* fp   = (float*)(ws + 444825600ull);
  float* c1   = (float*)(ws + 445766400ull);
  float* WqT  = (float*)(ws + 445785600ull);
  float* w2c2 = (float*)(ws + 446047744ull);

  k0_prep<<<dim3(256), dim3(256), 0, stream>>>(Wq, bk, bq, WqT, w2c2);
  k1_perb<<<dim3(BB), dim3(256), 0, stream>>>(pro, posx, bbox, Wqs1, bqs1, Wqs2, bqs2,
                                              Wr1, br1, Wr2, br2, Wk, WqT, bq, z, c1);
  k2_fp<<<dim3(BB), dim3(256), 0, stream>>>(posi, posl, z, c1, w2c2, fp);
  // z dead; wot overlays it
  kc_wot<<<dim3(KWO / 32, HH / 32), dim3(256), 0, stream>>>(Wo, wot);
  kc_pro<<<dim3(MPAD * HH / 8 / 256), dim3(256), 0, stream>>>(pro, proh);
  kc_wdt<<<dim3(NDP / 32, HH / 32), dim3(256), 0, stream>>>(Wd, wdt);
  kc_bdp<<<dim3(NDP / 256), dim3(256), 0, stream>>>(bd, bdp);
  k3_mfma<<<dim3(NDP / 128, MPAD / 128), dim3(256), 0, stream>>>(proh, wdt, bdp, params);
  k4_mfma<<<dim3(BB), dim3(256), 0, stream>>>(roi, params, fp, g1, be1, g2, be2, f2ws);
  // params dead; part overlays it
  k5_mfma<<<dim3(SK, BB / 64, HH / 128), dim3(256), 0, stream>>>(f2ws, wot, part);
  k5r_ln3<<<dim3(BB), dim3(256), 0, stream>>>(part, bo, g3, be3, (float*)d_out);
}

// Round 6
// 585.411 us; speedup vs baseline: 4.2937x; 1.2546x over previous
//
#include <hip/hip_runtime.h>
#include <hip/hip_bf16.h>

#define HH 256
#define DD 64
#define SS 49
#define BB 4800
#define PP 16384
#define NDP 32768
#define KWO 12544  // S*H
#define MPAD 4864  // BB padded to 128
#define SK 8       // split-K factor for K5
#define KCH 1568   // KWO / SK = 49 * 32

typedef unsigned int u32;
typedef unsigned short u16;
typedef __attribute__((ext_vector_type(8))) short bf16x8;
typedef __attribute__((ext_vector_type(4))) float f32x4;

__device__ __forceinline__ float bf2f(__hip_bfloat16 h) { return __bfloat162float(h); }

__device__ __forceinline__ void load_lds16(const void* g, void* l) {
  __builtin_amdgcn_global_load_lds(
      (const __attribute__((address_space(1))) unsigned int*)g,
      (__attribute__((address_space(3))) unsigned int*)l, 16, 0, 0);
}

// permutation of the params N-dim: param1 (n=h*64+d) -> [d][h]; param2 -> [h][d]
__device__ __forceinline__ int nperm(int n) {
  if (n < PP) { int h = n >> 6, d = n & 63; return d * HH + h; }
  int r = n - PP; int d = r >> 8, h = r & 255; return PP + h * DD + d;
}

__device__ __forceinline__ float wave_sum64(float v) {
#pragma unroll
  for (int off = 32; off > 0; off >>= 1) v += __shfl_xor(v, off);
  return v;
}

__device__ __forceinline__ float block_sum256(float v, float* red) {
  v = wave_sum64(v);
  int w = threadIdx.x >> 6;
  if ((threadIdx.x & 63) == 0) red[w] = v;
  __syncthreads();
  float r = red[0] + red[1] + red[2] + red[3];
  __syncthreads();
  return r;
}

// K0: w2[k] = sum_h Wq[k][h]*bk[h]; c2 = sum_h bq[h]*bk[h]  (WqT no longer needed)
__global__ void k0_prep(const float* __restrict__ Wq, const float* __restrict__ bk,
                        const float* __restrict__ bq, float* __restrict__ w2c2) {
  __shared__ float red[4];
  int k = blockIdx.x, h = threadIdx.x;
  float v = Wq[k * HH + h];
  float s = block_sum256(v * bk[h], red);
  if (h == 0) w2c2[k] = s;
  if (k == 0) {
    float s2 = block_sum256(bq[h] * bk[h], red);
    if (h == 0) w2c2[HH] = s2;
  }
}

// Prep k1 weights: z=0..3 transpose+cast {Wqs1,Wqs2,Wr1,Wk} -> [n][k] bf16; z=4 cast Wq.
__global__ __launch_bounds__(256) void kc_w1(
    const float* __restrict__ Wqs1, const float* __restrict__ Wqs2,
    const float* __restrict__ Wr1, const float* __restrict__ Wk,
    const float* __restrict__ Wq,
    u16* __restrict__ w1t, u16* __restrict__ w2t, u16* __restrict__ wr1t,
    u16* __restrict__ wkt, u16* __restrict__ wqh) {
  int t = threadIdx.x;
  int zi = blockIdx.z;
  if (zi == 4) {
    int row = blockIdx.y * 32 + (t >> 3), col = blockIdx.x * 32 + (t & 7) * 4;
    float4 v = *(const float4*)&Wq[row * HH + col];
    union { u16 u[4]; uint2 q; } pk;
    __hip_bfloat16 hb;
    hb = __float2bfloat16(v.x); pk.u[0] = *(u16*)&hb;
    hb = __float2bfloat16(v.y); pk.u[1] = *(u16*)&hb;
    hb = __float2bfloat16(v.z); pk.u[2] = *(u16*)&hb;
    hb = __float2bfloat16(v.w); pk.u[3] = *(u16*)&hb;
    *(uint2*)&wqh[row * HH + col] = pk.q;
    return;
  }
  const float* src = (zi == 0) ? Wqs1 : (zi == 1) ? Wqs2 : (zi == 2) ? Wr1 : Wk;
  u16* dst = (zi == 0) ? w1t : (zi == 1) ? w2t : (zi == 2) ? wr1t : wkt;
  __shared__ float tile[32][33];
  int n0 = blockIdx.x * 32, k0 = blockIdx.y * 32;
  {
    int kk = t >> 3, nn = (t & 7) * 4;
    float4 v = *(const float4*)&src[(k0 + kk) * HH + n0 + nn];
    tile[kk][nn + 0] = v.x;
    tile[kk][nn + 1] = v.y;
    tile[kk][nn + 2] = v.z;
    tile[kk][nn + 3] = v.w;
  }
  __syncthreads();
  {
    int nn = t >> 3, kk = (t & 7) * 4;
    union { u16 u[4]; uint2 q; } pk;
#pragma unroll
    for (int i = 0; i < 4; ++i) {
      __hip_bfloat16 hb = __float2bfloat16(tile[kk + i][nn]);
      pk.u[i] = *(u16*)&hb;
    }
    *(uint2*)&dst[(n0 + nn) * HH + k0 + kk] = pk.q;
  }
}

// ---- k1_mfma helpers: BM=64, 8 waves (2m x 4n), per-wave 32x64 output ----
__device__ __forceinline__ void g_gemm(const u16* aLb, const u16* __restrict__ Bg,
                                       int wm, int wn, int lg, int lr,
                                       f32x4 acc[2][4]) {
#pragma unroll
  for (int k0 = 0; k0 < HH; k0 += 32) {
    int colb = (k0 + (lg << 3)) << 1;
    bf16x8 af[2];
#pragma unroll
    for (int mi = 0; mi < 2; ++mi) {
      int row = wm * 32 + mi * 16 + lr;
      af[mi] = *(const bf16x8*)((const char*)aLb + (row << 9) +
                                (colb ^ ((row & 7) << 4)));
    }
    bf16x8 bfr[4];
#pragma unroll
    for (int ni = 0; ni < 4; ++ni) {
      int n = wn * 64 + ni * 16 + lr;
      bfr[ni] = *(const bf16x8*)&Bg[n * HH + k0 + (lg << 3)];
    }
#pragma unroll
    for (int mi = 0; mi < 2; ++mi)
#pragma unroll
      for (int ni = 0; ni < 4; ++ni)
        acc[mi][ni] = __builtin_amdgcn_mfma_f32_16x16x32_bf16(af[mi], bfr[ni], acc[mi][ni], 0, 0, 0);
  }
}

__device__ __forceinline__ void c_write(u16* xLb, f32x4 acc[2][4],
                                        const float* __restrict__ bias, bool dorelu,
                                        int wm, int wn, int lg, int lr) {
#pragma unroll
  for (int ni = 0; ni < 4; ++ni) {
    int col = wn * 64 + ni * 16 + lr;
    float bv = bias ? bias[col] : 0.f;
#pragma unroll
    for (int mi = 0; mi < 2; ++mi) {
#pragma unroll
      for (int j = 0; j < 4; ++j) {
        int row = wm * 32 + mi * 16 + (lg << 2) + j;
        float v = acc[mi][ni][j] + bv;
        if (dorelu) v = fmaxf(v, 0.f);
        __hip_bfloat16 hb = __float2bfloat16(v);
        *(u16*)((char*)xLb + (row << 9) + (((col << 1)) ^ ((row & 7) << 4))) = *(u16*)&hb;
      }
    }
  }
}

// K1: fused MLP chain via MFMA. BM=64, grid 75, 512 threads.
__global__ __launch_bounds__(512) void k1_mfma(
    const u16* __restrict__ proh, const float* __restrict__ posx,
    const float* __restrict__ bbox,
    const u16* __restrict__ w1t, const u16* __restrict__ w2t,
    const u16* __restrict__ wr1t, const u16* __restrict__ wkt,
    const u16* __restrict__ wqh,
    const float* __restrict__ bqs1, const float* __restrict__ bqs2,
    const float* __restrict__ br1, const float* __restrict__ Wr2,
    const float* __restrict__ br2, const float* __restrict__ bq,
    float* __restrict__ z, float* __restrict__ c1) {
  __shared__ u16 aL[16384];   // [64][512B] swz: pro, later px
  __shared__ u16 xL[16384];   // r1 -> t1 -> y
  __shared__ float red0[512], red1[512];
  __shared__ float scLoL[64], scHiL[64];
  const int t = threadIdx.x;
  const int w = t >> 6, l = t & 63;
  const int lg = l >> 4, lr = l & 15;
  const int wm = w >> 2, wn = w & 3;
  const int m0 = blockIdx.x * 64;

  // stage pro tile (pre-swizzled source)
#pragma unroll
  for (int i = 0; i < 4; ++i) {
    int c = i * 512 + t;
    int a = c * 16;
    int row = a >> 9, x0 = a & 511;
    int src = (m0 + row) * HH + ((x0 ^ ((row & 7) << 4)) >> 1);
    load_lds16(proh + src, (char*)aL + (size_t)(i * 512 + (w << 6)) * 16);
  }
  __syncthreads();

  // G3: r1 = relu(pro @ Wr1 + br1) -> xL
  {
    f32x4 acc[2][4] = {};
    g_gemm(aL, wr1t, wm, wn, lg, lr, acc);
    c_write(xL, acc, br1, true, wm, wn, lg, lr);
  }
  __syncthreads();
  // G4: ref = sigmoid(r1 @ Wr2 + br2); per-row scales
  {
    int row = t & 63, seg = t >> 6;
    float s0 = 0.f, s1 = 0.f;
#pragma unroll 8
    for (int hh = 0; hh < 32; ++hh) {
      int h = seg * 32 + hh;
      float rv = bf2f(*(const __hip_bfloat16*)((const char*)xL + (row << 9) +
                                               (((h << 1)) ^ ((row & 7) << 4))));
      s0 = fmaf(rv, Wr2[h * 2 + 0], s0);
      s1 = fmaf(rv, Wr2[h * 2 + 1], s1);
    }
    red0[row * 8 + seg] = s0;
    red1[row * 8 + seg] = s1;
  }
  __syncthreads();
  if (t < 64) {
    float s0 = br2[0], s1 = br2[1];
#pragma unroll
    for (int k = 0; k < 8; ++k) {
      s0 += red0[t * 8 + k];
      s1 += red1[t * 8 + k];
    }
    float r0 = 1.f / (1.f + __expf(-s0));
    float r1 = 1.f / (1.f + __expf(-s1));
    scHiL[t] = r0 / bbox[(m0 + t) * 4 + 2];
    scLoL[t] = r1 / bbox[(m0 + t) * 4 + 3];
  }
  // G1: t1 = relu(pro @ Wqs1 + bqs1) -> xL (after barrier)
  f32x4 acc1[2][4] = {};
  g_gemm(aL, w1t, wm, wn, lg, lr, acc1);
  __syncthreads();  // G4 xL reads done; scL ready
  c_write(xL, acc1, bqs1, true, wm, wn, lg, lr);
  __syncthreads();
  // G2: pos_t = t1 @ Wqs2 (+bqs2 later) -> regs
  f32x4 accp[2][4] = {};
  g_gemm(xL, w2t, wm, wn, lg, lr, accp);
  __syncthreads();  // xL(t1), aL(pro) reads done
  // scale: px = posx * (pos_t+bqs2) * sc -> aL
#pragma unroll
  for (int ni = 0; ni < 4; ++ni) {
    int col = wn * 64 + ni * 16 + lr;
    float bv = bqs2[col];
#pragma unroll
    for (int mi = 0; mi < 2; ++mi) {
#pragma unroll
      for (int j = 0; j < 4; ++j) {
        int row = wm * 32 + mi * 16 + (lg << 2) + j;
        float pt = accp[mi][ni][j] + bv;
        float sc = (col < 128) ? scLoL[row] : scHiL[row];
        float v = posx[(m0 + row) * HH + col] * pt * sc;
        __hip_bfloat16 hb = __float2bfloat16(v);
        *(u16*)((char*)aL + (row << 9) + (((col << 1)) ^ ((row & 7) << 4))) = *(u16*)&hb;
      }
    }
  }
  __syncthreads();
  // G5: y = px @ Wk -> xL
  {
    f32x4 acc[2][4] = {};
    g_gemm(aL, wkt, wm, wn, lg, lr, acc);
    c_write(xL, acc, nullptr, false, wm, wn, lg, lr);
  }
  __syncthreads();
  // c1 partials + G6: z = y @ Wq^T
  {
    int row = t & 63, seg = t >> 6;
    float s0 = 0.f;
#pragma unroll 8
    for (int hh = 0; hh < 32; ++hh) {
      int h = seg * 32 + hh;
      float yv = bf2f(*(const __hip_bfloat16*)((const char*)xL + (row << 9) +
                                               (((h << 1)) ^ ((row & 7) << 4))));
      s0 = fmaf(yv, bq[h], s0);
    }
    red0[row * 8 + seg] = s0;
  }
  f32x4 accz[2][4] = {};
  g_gemm(xL, wqh, wm, wn, lg, lr, accz);
  __syncthreads();
  if (t < 64) {
    float s = 0.f;
#pragma unroll
    for (int k = 0; k < 8; ++k) s += red0[t * 8 + k];
    c1[m0 + t] = s;
  }
#pragma unroll
  for (int ni = 0; ni < 4; ++ni) {
    int col = wn * 64 + ni * 16 + lr;
#pragma unroll
    for (int mi = 0; mi < 2; ++mi) {
#pragma unroll
      for (int j = 0; j < 4; ++j) {
        int row = wm * 32 + mi * 16 + (lg << 2) + j;
        z[(size_t)(m0 + row) * HH + col] = accz[mi][ni][j];
      }
    }
  }
}

// K2: fp[b,s] = posl[s]*(pos_img[s,b]·z[b] + c1[b]) + pos_img[s,b]·w2 + c2
__global__ __launch_bounds__(256) void k2_fp(
    const float* __restrict__ posi, const float* __restrict__ posl,
    const float* __restrict__ z, const float* __restrict__ c1,
    const float* __restrict__ w2c2, float* __restrict__ fp) {
  int b = blockIdx.x, t = threadIdx.x;
  int l = t & 63, w = t >> 6;
  float4 zv = *(const float4*)&z[b * HH + l * 4];
  float4 wv = *(const float4*)&w2c2[l * 4];
  float c1b = c1[b];
  float c2 = w2c2[HH];
  for (int s = w; s < SS; s += 4) {
    float4 pi = *(const float4*)&posi[((size_t)s * BB + b) * HH + l * 4];
    float d1 = pi.x * zv.x + pi.y * zv.y + pi.z * zv.z + pi.w * zv.w;
    float d2 = pi.x * wv.x + pi.y * wv.y + pi.z * wv.z + pi.w * wv.w;
#pragma unroll
    for (int off = 32; off > 0; off >>= 1) {
      d1 += __shfl_xor(d1, off);
      d2 += __shfl_xor(d2, off);
    }
    if (l == 0) fp[b * SS + s] = posl[s] * (d1 + c1b) + d2 + c2;
  }
}

// cast pro -> bf16, padded to MPAD rows (zeros in pad)
__global__ __launch_bounds__(256) void kc_pro(const float* __restrict__ pro,
                                              u16* __restrict__ proh) {
  int tg = blockIdx.x * 256 + threadIdx.x;
  int e0 = tg * 8;
  int row = e0 >> 8;
  union { u16 u[8]; uint4 v; } pk;
  if (row < BB) {
    float4 v0 = *(const float4*)&pro[e0];
    float4 v1 = *(const float4*)&pro[e0 + 4];
    float vv[8] = {v0.x, v0.y, v0.z, v0.w, v1.x, v1.y, v1.z, v1.w};
#pragma unroll
    for (int i = 0; i < 8; ++i) {
      __hip_bfloat16 hb = __float2bfloat16(vv[i]);
      pk.u[i] = *(u16*)&hb;
    }
  } else {
    pk.v = make_uint4(0, 0, 0, 0);
  }
  *(uint4*)&proh[e0] = pk.v;
}

// transpose+cast Wd (256 x 32768 f32) -> wdt[nperm(n)][k] bf16
__global__ __launch_bounds__(256) void kc_wdt(const float* __restrict__ Wd,
                                              u16* __restrict__ wdt) {
  __shared__ float tile[32][33];
  int n0 = blockIdx.x * 32;
  int k0 = blockIdx.y * 32;
  int t = threadIdx.x;
  {
    int kk = t >> 3, nn = (t & 7) * 4;
    float4 v = *(const float4*)&Wd[(size_t)(k0 + kk) * NDP + n0 + nn];
    tile[kk][nn + 0] = v.x;
    tile[kk][nn + 1] = v.y;
    tile[kk][nn + 2] = v.z;
    tile[kk][nn + 3] = v.w;
  }
  __syncthreads();
  {
    int nn = t >> 3, kk = (t & 7) * 4;
    union { u16 u[4]; uint2 v; } pk;
#pragma unroll
    for (int i = 0; i < 4; ++i) {
      __hip_bfloat16 hb = __float2bfloat16(tile[kk + i][nn]);
      pk.u[i] = *(u16*)&hb;
    }
    int np = nperm(n0 + nn);
    *(uint2*)&wdt[(size_t)np * HH + k0 + kk] = pk.v;
  }
}

// bdp[nperm(n)] = bd[n]
__global__ void kc_bdp(const float* __restrict__ bd, float* __restrict__ bdp) {
  int n = blockIdx.x * 256 + threadIdx.x;
  bdp[nperm(n)] = bd[n];
}

// transpose+cast Wo (12544 x 256 f32) -> woT (256 x 12544 bf16)
__global__ __launch_bounds__(256) void kc_wot(const float* __restrict__ Wo,
                                              u16* __restrict__ wot) {
  __shared__ float tile[32][33];
  int k0 = blockIdx.x * 32;
  int n0 = blockIdx.y * 32;
  int t = threadIdx.x;
  {
    int kk = t >> 3, nn = (t & 7) * 4;
    float4 v = *(const float4*)&Wo[(size_t)(k0 + kk) * HH + n0 + nn];
    tile[kk][nn + 0] = v.x;
    tile[kk][nn + 1] = v.y;
    tile[kk][nn + 2] = v.z;
    tile[kk][nn + 3] = v.w;
  }
  __syncthreads();
  {
    int nn = t >> 3, kk = (t & 7) * 4;
    union { u16 u[4]; uint2 v; } pk;
#pragma unroll
    for (int i = 0; i < 4; ++i) {
      __hip_bfloat16 hb = __float2bfloat16(tile[kk + i][nn]);
      pk.u[i] = *(u16*)&hb;
    }
    *(uint2*)&wot[(size_t)(n0 + nn) * KWO + k0 + kk] = pk.v;
  }
}

// K3: params = proh @ wdt^T + bdp via bf16 MFMA. M=4800(pad 4864), N=32768, K=256.
__global__ __launch_bounds__(256) void k3_mfma(const u16* __restrict__ proh,
                                               const u16* __restrict__ wdt,
                                               const float* __restrict__ bdp,
                                               u16* __restrict__ params) {
  __shared__ char smem[32768];
  u16* Al = (u16*)smem;
  u16* Bl = (u16*)(smem + 8192);
  const int t = threadIdx.x;
  const int w = t >> 6, l = t & 63;
  const int n0 = blockIdx.x * 128;
  const int m0 = blockIdx.y * 128;
  const int wr = w >> 1, wc = w & 1;
  f32x4 acc[4][4] = {};

  for (int k0 = 0; k0 < HH; k0 += 32) {
#pragma unroll
    for (int i = 0; i < 2; ++i) {
      int c = i * 256 + t;
      int r = c >> 2, kq = (c & 3) * 8;
      int wbase = (i * 256 + (w << 6)) * 8;
      load_lds16(proh + (size_t)(m0 + r) * HH + k0 + kq, Al + wbase);
      load_lds16(wdt + (size_t)(n0 + r) * HH + k0 + kq, Bl + wbase);
    }
    __syncthreads();
    bf16x8 af[4], bfr[4];
#pragma unroll
    for (int mi = 0; mi < 4; ++mi)
      af[mi] = *(const bf16x8*)&Al[(wr * 64 + mi * 16 + (l & 15)) * 32 + (l >> 4) * 8];
#pragma unroll
    for (int ni = 0; ni < 4; ++ni)
      bfr[ni] = *(const bf16x8*)&Bl[(wc * 64 + ni * 16 + (l & 15)) * 32 + (l >> 4) * 8];
#pragma unroll
    for (int mi = 0; mi < 4; ++mi)
#pragma unroll
      for (int ni = 0; ni < 4; ++ni)
        acc[mi][ni] = __builtin_amdgcn_mfma_f32_16x16x32_bf16(af[mi], bfr[ni], acc[mi][ni], 0, 0, 0);
    __syncthreads();
  }
  u16* cb = (u16*)smem;
#pragma unroll
  for (int ni = 0; ni < 4; ++ni) {
    int col = wc * 64 + ni * 16 + (l & 15);
    float bias = bdp[n0 + col];
#pragma unroll
    for (int mi = 0; mi < 4; ++mi) {
#pragma unroll
      for (int j = 0; j < 4; ++j) {
        int row = wr * 64 + mi * 16 + ((l >> 4) << 2) + j;
        __hip_bfloat16 hb = __float2bfloat16(acc[mi][ni][j] + bias);
        cb[row * 128 + col] = *(u16*)&hb;
      }
    }
  }
  __syncthreads();
#pragma unroll
  for (int i = 0; i < 8; ++i) {
    int idx = i * 256 + t;
    int row = idx >> 4, cc = (idx & 15) * 8;
    if (m0 + row < BB)
      *(uint4*)&params[(size_t)(m0 + row) * NDP + n0 + cc] = *(const uint4*)&cb[row * 128 + cc];
  }
}

// K4: per-b dynamic conv via MFMA (params permuted: param1T [d][h], param2T [h][d]).
__global__ __launch_bounds__(256) void k4_mfma(
    const float* __restrict__ roi, const u16* __restrict__ params,
    const float* __restrict__ fpbuf,
    const float* __restrict__ g1, const float* __restrict__ be1,
    const float* __restrict__ g2, const float* __restrict__ be2,
    u16* __restrict__ f2ws) {
  __shared__ u16 bufA[16384];
  __shared__ u16 bufP1[16384];
  __shared__ u16 f1L[4096];
  __shared__ float fpL[64];
  __shared__ float g1L[64], b1L[64], g2L[256], b2L[256];

  const int b = blockIdx.x;
  const int t = threadIdx.x;
  const int w = t >> 6, l = t & 63;
  const int lg = l >> 4, lr = l & 15;
  const int swz = (lr & 7) << 4;

#pragma unroll
  for (int i = 0; i < 8; ++i) {
    int c = i * 256 + t;
    int a = c * 16;
    int row = a >> 9;
    int x0 = a & 511;
    int src = b * NDP + row * HH + ((x0 ^ ((row & 7) << 4)) >> 1);
    load_lds16(params + src, (char*)bufP1 + (size_t)(i * 256 + (w << 6)) * 16);
  }
  uint4 p2r[8];
#pragma unroll
  for (int i = 0; i < 8; ++i) {
    int c = i * 256 + t;
    p2r[i] = *(const uint4*)&params[(size_t)b * NDP + PP + c * 8];
  }
#pragma unroll
  for (int i = 0; i < 16; ++i) {
    int idx = i * 256 + t;
    int row = idx >> 6, c4 = (idx & 63) << 2;
    union { u16 u[4]; unsigned long long v; } pk;
    if (row < SS) {
      float4 v = *(const float4*)&roi[((size_t)row * BB + b) * HH + c4];
      __hip_bfloat16 h0 = __float2bfloat16(v.x), h1 = __float2bfloat16(v.y);
      __hip_bfloat16 h2 = __float2bfloat16(v.z), h3 = __float2bfloat16(v.w);
      pk.u[0] = *(u16*)&h0; pk.u[1] = *(u16*)&h1;
      pk.u[2] = *(u16*)&h2; pk.u[3] = *(u16*)&h3;
    } else {
      pk.v = 0ull;
    }
    int ab = (row << 9) + (((c4 << 1)) ^ ((row & 7) << 4));
    *(unsigned long long*)((char*)bufA + ab) = pk.v;
  }
  if (t < 64) {
    fpL[t] = (t < SS) ? fpbuf[b * SS + t] : 0.f;
    g1L[t] = g1[t];
    b1L[t] = be1[t];
  }
  g2L[t] = g2[t];
  b2L[t] = be2[t];
  __syncthreads();

  f32x4 acc1[4] = {};
#pragma unroll
  for (int k0 = 0; k0 < HH; k0 += 32) {
    int colb = ((k0 + (lg << 3)) << 1) ^ swz;
    const bf16x8 af = *(const bf16x8*)((const char*)bufA + ((w * 16 + lr) << 9) + colb);
    bf16x8 bfr[4];
#pragma unroll
    for (int ni = 0; ni < 4; ++ni)
      bfr[ni] = *(const bf16x8*)((const char*)bufP1 + ((ni * 16 + lr) << 9) + colb);
#pragma unroll
    for (int ni = 0; ni < 4; ++ni)
      acc1[ni] = __builtin_amdgcn_mfma_f32_16x16x32_bf16(af, bfr[ni], acc1[ni], 0, 0, 0);
  }
  __syncthreads();

#pragma unroll
  for (int i = 0; i < 8; ++i) {
    int c = i * 256 + t;
    int a = c * 16;
    int row = a >> 7;
    int x0 = a & 127;
    *(uint4*)((char*)bufA + (row << 7) + (x0 ^ ((row & 7) << 4))) = p2r[i];
  }

#pragma unroll
  for (int j = 0; j < 4; ++j) {
    int s = w * 16 + (lg << 2) + j;
    float fpv = fpL[s];
    float x[4], sum = 0.f, sq = 0.f;
#pragma unroll
    for (int ni = 0; ni < 4; ++ni) {
      x[ni] = acc1[ni][j] + fpv;
      sum += x[ni];
      sq += x[ni] * x[ni];
    }
#pragma unroll
    for (int off = 1; off < 16; off <<= 1) {
      sum += __shfl_xor(sum, off);
      sq += __shfl_xor(sq, off);
    }
    float m = sum * (1.f / 64.f);
    float rs = rsqrtf(sq * (1.f / 64.f) - m * m + 1e-5f);
#pragma unroll
    for (int ni = 0; ni < 4; ++ni) {
      int d = ni * 16 + lr;
      float o = fmaxf((x[ni] - m) * rs * g1L[d] + b1L[d], 0.f);
      __hip_bfloat16 hb = __float2bfloat16(o);
      *(u16*)((char*)f1L + (s << 7) + ((d << 1) ^ ((s & 7) << 4))) = *(u16*)&hb;
    }
  }
  __syncthreads();

  f32x4 acc2[16] = {};
#pragma unroll
  for (int k0 = 0; k0 < 64; k0 += 32) {
    int colb = ((k0 + (lg << 3)) << 1) ^ swz;
    const bf16x8 af = *(const bf16x8*)((const char*)f1L + ((w * 16 + lr) << 7) + colb);
#pragma unroll
    for (int ni = 0; ni < 16; ++ni) {
      const bf16x8 bfr = *(const bf16x8*)((const char*)bufA + ((ni * 16 + lr) << 7) + colb);
      acc2[ni] = __builtin_amdgcn_mfma_f32_16x16x32_bf16(af, bfr, acc2[ni], 0, 0, 0);
    }
  }

#pragma unroll
  for (int j = 0; j < 4; ++j) {
    int s = w * 16 + (lg << 2) + j;
    float sum = 0.f, sq = 0.f;
#pragma unroll
    for (int ni = 0; ni < 16; ++ni) {
      float v = acc2[ni][j];
      sum += v;
      sq += v * v;
    }
#pragma unroll
    for (int off = 1; off < 16; off <<= 1) {
      sum += __shfl_xor(sum, off);
      sq += __shfl_xor(sq, off);
    }
    float m = sum * (1.f / 256.f);
    float rs = rsqrtf(sq * (1.f / 256.f) - m * m + 1e-5f);
    if (s < SS) {
#pragma unroll
      for (int ni = 0; ni < 16; ++ni) {
        int h = ni * 16 + lr;
        float o = fmaxf((acc2[ni][j] - m) * rs * g2L[h] + b2L[h], 0.f);
        __hip_bfloat16 hb = __float2bfloat16(o);
        f2ws[(size_t)b * KWO + s * HH + h] = *(u16*)&hb;
      }
    }
  }
}

// K5: partial[sk][m][n] = f2ws[m, kchunk] @ woT[n, kchunk]^T, split-K bf16 MFMA.
__global__ __launch_bounds__(256) void k5_mfma(const u16* __restrict__ f2,
                                               const u16* __restrict__ wot,
                                               float* __restrict__ part) {
  __shared__ char smem[12288];
  u16* Al = (u16*)smem;
  u16* Bl = (u16*)(smem + 4096);
  const int t = threadIdx.x;
  const int w = t >> 6, l = t & 63;
  const int sk = blockIdx.x;
  const int m0 = blockIdx.y * 64;
  const int n0 = blockIdx.z * 128;
  const size_t kbase = (size_t)sk * KCH;
  const int wr = w >> 1, wc = w & 1;
  f32x4 acc[2][4] = {};

  for (int k0 = 0; k0 < KCH; k0 += 32) {
    {
      int r = t >> 2, kq = (t & 3) * 8;
      int wbase = (w << 6) * 8;
      load_lds16(f2 + (size_t)(m0 + r) * KWO + kbase + k0 + kq, Al + wbase);
    }
#pragma unroll
    for (int i = 0; i < 2; ++i) {
      int c = i * 256 + t;
      int r = c >> 2, kq = (c & 3) * 8;
      int wbase = (i * 256 + (w << 6)) * 8;
      load_lds16(wot + (size_t)(n0 + r) * KWO + kbase + k0 + kq, Bl + wbase);
    }
    __syncthreads();
    bf16x8 af[2], bfr[4];
#pragma unroll
    for (int mi = 0; mi < 2; ++mi)
      af[mi] = *(const bf16x8*)&Al[(wr * 32 + mi * 16 + (l & 15)) * 32 + (l >> 4) * 8];
#pragma unroll
    for (int ni = 0; ni < 4; ++ni)
      bfr[ni] = *(const bf16x8*)&Bl[(wc * 64 + ni * 16 + (l & 15)) * 32 + (l >> 4) * 8];
#pragma unroll
    for (int mi = 0; mi < 2; ++mi)
#pragma unroll
      for (int ni = 0; ni < 4; ++ni)
        acc[mi][ni] = __builtin_amdgcn_mfma_f32_16x16x32_bf16(af[mi], bfr[ni], acc[mi][ni], 0, 0, 0);
    __syncthreads();
  }
#pragma unroll
  for (int mi = 0; mi < 2; ++mi) {
#pragma unroll
    for (int j = 0; j < 4; ++j) {
      int m = m0 + wr * 32 + mi * 16 + ((l >> 4) << 2) + j;
#pragma unroll
      for (int ni = 0; ni < 4; ++ni) {
        int n = n0 + wc * 64 + ni * 16 + (l & 15);
        part[((size_t)sk * BB + m) * HH + n] = acc[mi][ni][j];
      }
    }
  }
}

// K5R: reduce partials + bias, LN3 + relu -> out
__global__ __launch_bounds__(256) void k5r_ln3(
    const float* __restrict__ part, const float* __restrict__ bo,
    const float* __restrict__ g3, const float* __restrict__ be3,
    float* __restrict__ out) {
  __shared__ float red[4];
  int b = blockIdx.x, t = threadIdx.x;
  float v = bo[t];
#pragma unroll
  for (int sk = 0; sk < SK; ++sk) v += part[((size_t)sk * BB + b) * HH + t];
  float m = block_sum256(v, red) * (1.f / HH);
  float d = v - m;
  float var = block_sum256(d * d, red) * (1.f / HH);
  out[b * HH + t] = fmaxf(fmaf(d * rsqrtf(var + 1e-5f), g3[t], be3[t]), 0.f);
}

extern "C" void kernel_launch(void* const* d_in, const int* in_sizes, int n_in,
                              void* d_out, int out_size, void* d_ws, size_t ws_size,
                              hipStream_t stream) {
  const float* pro  = (const float*)d_in[0];
  const float* roi  = (const float*)d_in[1];
  const float* posx = (const float*)d_in[2];
  const float* posi = (const float*)d_in[3];
  const float* posl = (const float*)d_in[4];
  const float* bbox = (const float*)d_in[5];
  const float* Wd   = (const float*)d_in[6];
  const float* bd   = (const float*)d_in[7];
  const float* Wqs1 = (const float*)d_in[8];
  const float* bqs1 = (const float*)d_in[9];
  const float* Wqs2 = (const float*)d_in[10];
  const float* bqs2 = (const float*)d_in[11];
  const float* Wr1  = (const float*)d_in[12];
  const float* br1  = (const float*)d_in[13];
  const float* Wr2  = (const float*)d_in[14];
  const float* br2  = (const float*)d_in[15];
  const float* Wq   = (const float*)d_in[16];
  const float* bq   = (const float*)d_in[17];
  const float* Wk   = (const float*)d_in[18];
  const float* bk   = (const float*)d_in[19];
  const float* g1   = (const float*)d_in[20];
  const float* be1  = (const float*)d_in[21];
  const float* g2   = (const float*)d_in[22];
  const float* be2  = (const float*)d_in[23];
  const float* g3   = (const float*)d_in[24];
  const float* be3  = (const float*)d_in[25];
  const float* Wo   = (const float*)d_in[26];
  const float* bo   = (const float*)d_in[27];

  // ws layout (bytes):
  //   k1 weights @ 0 (5 x 131072 = 655360) -- dead after k1; params overlays
  //   params/part @ 0          (314572800 / 39321600)
  //   f2ws        @ 314572800  (120422400); proh/wdt alias (dead after k3)
  //   z/wot       @ 434995200  (z dead after k2; wot overlays)
  //   bdp         @ 441417728  (131072)
  //   fp          @ 444825600  (940800)
  //   c1          @ 445766400  (19200)
  //   w2c2        @ 446047744  (1040)
  char* ws = (char*)d_ws;
  u16* w1t  = (u16*)(ws + 0ull);
  u16* w2t  = (u16*)(ws + 131072ull);
  u16* wr1t = (u16*)(ws + 262144ull);
  u16* wkt  = (u16*)(ws + 393216ull);
  u16* wqh  = (u16*)(ws + 524288ull);
  u16* params = (u16*)(ws + 0ull);
  float* part = (float*)(ws + 0ull);
  u16* f2ws   = (u16*)(ws + 314572800ull);
  u16* proh   = (u16*)(ws + 314572800ull);
  u16* wdt    = (u16*)(ws + 317063168ull);
  float* z    = (float*)(ws + 434995200ull);
  u16* wot    = (u16*)(ws + 434995200ull);
  float* bdp  = (float*)(ws + 441417728ull);
  float* fp   = (float*)(ws + 444825600ull);
  float* c1   = (float*)(ws + 445766400ull);
  float* w2c2 = (float*)(ws + 446047744ull);

  kc_pro<<<dim3(MPAD * HH / 8 / 256), dim3(256), 0, stream>>>(pro, proh);
  kc_w1<<<dim3(8, 8, 5), dim3(256), 0, stream>>>(Wqs1, Wqs2, Wr1, Wk, Wq,
                                                 w1t, w2t, wr1t, wkt, wqh);
  k0_prep<<<dim3(256), dim3(256), 0, stream>>>(Wq, bk, bq, w2c2);
  k1_mfma<<<dim3(BB / 64), dim3(512), 0, stream>>>(proh, posx, bbox, w1t, w2t, wr1t,
                                                   wkt, wqh, bqs1, bqs2, br1, Wr2,
                                                   br2, bq, z, c1);
  k2_fp<<<dim3(BB), dim3(256), 0, stream>>>(posi, posl, z, c1, w2c2, fp);
  // z dead; wot overlays it
  kc_wot<<<dim3(KWO / 32, HH / 32), dim3(256), 0, stream>>>(Wo, wot);
  kc_wdt<<<dim3(NDP / 32, HH / 32), dim3(256), 0, stream>>>(Wd, wdt);
  kc_bdp<<<dim3(NDP / 256), dim3(256), 0, stream>>>(bd, bdp);
  // k1 weights dead; k3 overwrites params region
  k3_mfma<<<dim3(NDP / 128, MPAD / 128), dim3(256), 0, stream>>>(proh, wdt, bdp, params);
  k4_mfma<<<dim3(BB), dim3(256), 0, stream>>>(roi, params, fp, g1, be1, g2, be2, f2ws);
  // params dead; part overlays it
  k5_mfma<<<dim3(SK, BB / 64, HH / 128), dim3(256), 0, stream>>>(f2ws, wot, part);
  k5r_ln3<<<dim3(BB), dim3(256), 0, stream>>>(part, bo, g3, be3, (float*)d_out);
}